// Round 10
// baseline (710.932 us; speedup 1.0000x reference)
//
#include <hip/hip_runtime.h>
#include <hip/hip_bf16.h>
#include <stdint.h>

#define DEV __device__ __forceinline__

typedef __attribute__((ext_vector_type(8))) short short8;
typedef __attribute__((ext_vector_type(4))) float f32x4;

#define B_ 2
#define S_ 4096
#define E_ 2048
#define H_ 16
#define D_ 128

#define BAR() asm volatile("s_barrier" ::: "memory")
#define LGKM0() asm volatile("s_waitcnt lgkmcnt(0)" ::: "memory")
#define VMC(N) asm volatile("s_waitcnt vmcnt(" #N ")" ::: "memory")

DEV unsigned short f2bf(float x) {
  union { float f; uint32_t u; } a; a.f = x;
  uint32_t r = a.u + 0x7fffu + ((a.u >> 16) & 1u);
  return (unsigned short)(r >> 16);
}

DEV unsigned int cvt_pk_bf16(float a, float b) {
  unsigned int r;
  asm("v_cvt_pk_bf16_f32 %0, %1, %2" : "=v"(r) : "v"(a), "v"(b));
  return r;
}

DEV float exp2f_(float x) { return __builtin_amdgcn_exp2f(x); }

DEV void glds16(const void* g, void* l) {
  __builtin_amdgcn_global_load_lds(
      (const __attribute__((address_space(1))) uint32_t*)g,
      (__attribute__((address_space(3))) uint32_t*)l, 16, 0, 0);
}

// one kernel converts all three f32 inputs to bf16 (saves 2 launch overheads)
__global__ __launch_bounds__(256) void cvtk3(
    const float* __restrict__ x, const float* __restrict__ wq,
    const float* __restrict__ wo, unsigned short* __restrict__ xb,
    unsigned short* __restrict__ wqb, unsigned short* __restrict__ wob) {
  const int n1 = (B_ * S_ * E_) / 4, n2 = (3 * E_ * E_) / 4, n3 = (E_ * E_) / 4;
  int i = blockIdx.x * blockDim.x + threadIdx.x;
  int stride = gridDim.x * blockDim.x;
  for (; i < n1 + n2 + n3; i += stride) {
    const float4* s;
    ushort4* d;
    int j;
    if (i < n1) { s = (const float4*)x; d = (ushort4*)xb; j = i; }
    else if (i < n1 + n2) { s = (const float4*)wq; d = (ushort4*)wqb; j = i - n1; }
    else { s = (const float4*)wo; d = (ushort4*)wob; j = i - n1 - n2; }
    float4 v = s[j];
    ushort4 o;
    o.x = f2bf(v.x); o.y = f2bf(v.y); o.z = f2bf(v.z); o.w = f2bf(v.w);
    d[j] = o;
  }
}

// C = A(MxK) * B(NxK)^T, 256x256 tile, BK=64, 8-phase schedule with counted
// vmcnt (T2+T3+T4+T5 per m201). 8 waves (2M x 4N), per-wave C = 128x64.
template<int OUT_F32>
__global__ __launch_bounds__(512, 2) void gemm256(
    const unsigned short* __restrict__ A,
    const unsigned short* __restrict__ Bm,
    void* __restrict__ Cp,
    const float* __restrict__ bias,
    int M, int N, int K, int nbn)
{
  __shared__ __align__(16) unsigned char lds[131072];
  const int NT = K >> 6;
  const int K2 = K * 2;
  int cpx = gridDim.x >> 3;
  int bid = (blockIdx.x & 7) * cpx + (blockIdx.x >> 3);
  int bm = bid / nbn, bn = bid % nbn;
  int m0 = bm * 256, n0 = bn * 256;
  int t = threadIdx.x, lane = t & 63, wv = t >> 6;
  int lo = lane & 15, hi = lane >> 4;
  int wm = wv >> 2, wn = wv & 3;

  int colsw = ((t & 7) * 16) ^ (((t >> 3) & 7) << 4);
  const unsigned char* gA = (const unsigned char*)A + (size_t)(m0 + (t >> 3)) * K2 + colsw;
  const unsigned char* gB = (const unsigned char*)Bm + (size_t)(n0 + (t >> 3)) * K2 + colsw;

  int swzl = (lo & 7) << 4;
  int colk0 = (hi * 16) ^ swzl;
  int colk1 = (64 + hi * 16) ^ swzl;
  unsigned char* rdA = lds + wm * 16384 + lo * 128;
  unsigned char* rdB = lds + 32768 + (wn >> 1) * 16384 + ((wn & 1) * 64 + lo) * 128;

  f32x4 acc[8][4] = {};

  auto STG = [&](int isA, int d, int h, int kt) {
    if (kt >= NT) return;
    const unsigned char* g = (isA ? gA : gB) + (size_t)h * 128 * K2 + (size_t)kt * 128;
    unsigned char* l = lds + (isA ? 0 : 32768) + d * 65536 + h * 16384 + wv * 1024;
    glds16(g, l);
    glds16(g + (size_t)64 * K2, l + 8192);
  };
  auto DSA = [&](int d, int g4, int colk, short8* dst) {
#pragma unroll
    for (int i = 0; i < 4; ++i)
      dst[i] = *(const short8*)(rdA + d * 65536 + (g4 * 4 + i) * 2048 + colk);
  };
  auto DSB = [&](int d, int colk, short8* dst) {
#pragma unroll
    for (int i = 0; i < 4; ++i)
      dst[i] = *(const short8*)(rdB + d * 65536 + i * 2048 + colk);
  };
  auto MM = [&](int g4, short8* a, short8* b) {
    __builtin_amdgcn_s_setprio(1);
#pragma unroll
    for (int i = 0; i < 4; ++i)
#pragma unroll
      for (int j = 0; j < 4; ++j)
        acc[g4 * 4 + i][j] =
            __builtin_amdgcn_mfma_f32_16x16x32_bf16(a[i], b[j], acc[g4 * 4 + i][j], 0, 0, 0);
    __builtin_amdgcn_s_setprio(0);
  };

  STG(1, 0, 0, 0); STG(1, 0, 1, 0); STG(0, 0, 0, 0); STG(0, 0, 1, 0);
  STG(0, 1, 0, 1); STG(0, 1, 1, 1);
  VMC(4);
  BAR();

  short8 aT[4], aU[4], b0[4], b1[4];
  const int TL = (NT >> 1) - 1;
  for (int it = 0; it <= TL; ++it) {
    int j0 = 2 * it;
    DSA(0, 0, colk0, aT); DSB(0, colk0, b0);
    STG(1, 1, 0, j0 + 1);
    BAR(); MM(0, aT, b0); LGKM0(); BAR();
    DSA(0, 1, colk0, aU); DSB(0, colk1, b1);
    STG(1, 1, 1, j0 + 1);
    BAR(); MM(1, aU, b0); LGKM0(); BAR();
    DSA(0, 0, colk1, aT);
    STG(0, 0, 0, j0 + 2);
    BAR(); MM(0, aT, b1); LGKM0(); BAR();
    DSA(0, 1, colk1, aU);
    STG(0, 0, 1, j0 + 2);
    BAR(); MM(1, aU, b1); LGKM0();
    if (it == TL) { VMC(0); } else { VMC(4); }
    BAR();
    DSA(1, 0, colk0, aT); DSB(1, colk0, b0);
    STG(1, 0, 0, j0 + 2);
    BAR(); MM(0, aT, b0); LGKM0(); BAR();
    DSA(1, 1, colk0, aU); DSB(1, colk1, b1);
    STG(1, 0, 1, j0 + 2);
    BAR(); MM(1, aU, b0); LGKM0(); BAR();
    DSA(1, 0, colk1, aT);
    STG(0, 1, 0, j0 + 3);
    BAR(); MM(0, aT, b1); LGKM0(); BAR();
    DSA(1, 1, colk1, aU);
    STG(0, 1, 1, j0 + 3);
    BAR(); MM(1, aU, b1); LGKM0(); VMC(4);
    BAR();
  }

  if constexpr (OUT_F32) {
    float* C = (float*)Cp;
#pragma unroll
    for (int mf = 0; mf < 8; ++mf)
#pragma unroll
      for (int nf = 0; nf < 4; ++nf) {
        int row = m0 + wm * 128 + mf * 16 + hi * 4;
        int col = n0 + wn * 64 + nf * 16 + lo;
        float bv = bias[col];
#pragma unroll
        for (int r = 0; r < 4; ++r)
          C[(size_t)(row + r) * N + col] = acc[mf][nf][r] + bv;
      }
  } else {
    unsigned short* C = (unsigned short*)Cp;
#pragma unroll
    for (int mf = 0; mf < 8; ++mf)
#pragma unroll
      for (int nf = 0; nf < 4; ++nf) {
        int row = m0 + wm * 128 + mf * 16 + hi * 4;
        int col = n0 + wn * 64 + nf * 16 + lo;
#pragma unroll
        for (int r = 0; r < 4; ++r)
          C[(size_t)(row + r) * N + col] = f2bf(acc[mf][nf][r]);
      }
  }
}

// vt[b,h,d,s] = qkv[b,s,2,h,d]
__global__ __launch_bounds__(256) void transpose_v(const unsigned short* __restrict__ qkv,
                                                   unsigned short* __restrict__ vt) {
  __shared__ __align__(16) unsigned char tl[32768];
  int bid = blockIdx.x;
  int st = bid & 31, bh = bid >> 5;
  int h = bh & 15, b = bh >> 4;
  int s0 = st * 128;
  int t = threadIdx.x, c = t & 15, rr = t >> 4;
#pragma unroll
  for (int i = 0; i < 8; ++i) {
    int s = rr + i * 16;
    const unsigned short* g = qkv + ((((size_t)b * S_ + s0 + s) * 3 + 2) * H_ + h) * D_ + c * 8;
    *(uint4*)(tl + s * 256 + ((c * 16) ^ (((s >> 3) & 7) << 4))) = *(const uint4*)g;
  }
  __syncthreads();
#pragma unroll
  for (int i = 0; i < 8; ++i) {
    int d = rr + i * 16;
    unsigned int w[4];
#pragma unroll
    for (int jj = 0; jj < 4; ++jj) {
      int s_a = c * 8 + jj * 2;
      unsigned int u0 = *(const unsigned short*)(tl + s_a * 256 + ((d * 2) ^ ((c & 7) << 4)));
      unsigned int u1 = *(const unsigned short*)(tl + (s_a + 1) * 256 + ((d * 2) ^ ((c & 7) << 4)));
      w[jj] = u0 | (u1 << 16);
    }
    uint4 val; val.x = w[0]; val.y = w[1]; val.z = w[2]; val.w = w[3];
    unsigned short* g = vt + (((size_t)b * H_ + h) * D_ + d) * S_ + s0 + c * 8;
    *(uint4*)g = val;
  }
}

// Flash attention, reference's extra l_ij semantics, KV block = 128.
// 8 waves x 32 q rows = 256-q block. DEFERRED PV: iter j runs QK(j) [LDS+MFMA]
// || PV(j-1) [LDS+MFMA] || softmax(j) [VALU] in one scheduling region (oacc
// RAW chain orders PV-add before the alpha-rescale). P in registers (permlane).
// LDS: K 32K | V0 32K | V1 32K = 96K. 2 barriers/iter. R8 register diet.
__global__ __launch_bounds__(512, 2) void attn_fwd(
    const unsigned short* __restrict__ qkv,  // [B,S,3,H,D] bf16
    const unsigned short* __restrict__ vt,   // [B,H,D,S] bf16
    unsigned short* __restrict__ abuf)       // [B,S,H*D] bf16
{
  __shared__ __align__(16) unsigned char lds[98304];
  unsigned char* lK = lds;  // K (single-buffered); V dbuf at 32768 + sel*32768

  int bid = (blockIdx.x & 7) * 64 + (blockIdx.x >> 3);
  int qb = bid & 15, bh = bid >> 4;
  int h = bh & 15, b = bh >> 4;
  int t = threadIdx.x, lane = t & 63, wv = t >> 6;
  int hi = lane >> 4, lo = lane & 15;
  int q0 = qb * 256;
  const float c1 = 0.12751744f;  // (1/sqrt(128)) * log2(e)

  short8 qf[2][4];
#pragma unroll
  for (int qj = 0; qj < 2; ++qj) {
    const unsigned short* qbase =
        qkv + ((((size_t)b * S_ + q0 + wv * 32 + qj * 16 + lo) * 3 + 0) * H_ + h) * D_;
#pragma unroll
    for (int ks = 0; ks < 4; ++ks)
      qf[qj][ks] = *(const short8*)(qbase + ks * 32 + hi * 8);
  }

  int sw = ((t & 15) * 16) ^ (((t >> 4) & 7) << 4);
  const unsigned char* gkb =
      (const unsigned char*)(qkv + (((size_t)b * S_ * 3 + 1) * H_ + h) * D_) +
      (size_t)(t >> 4) * 12288 + sw;
  const unsigned char* gvb =
      (const unsigned char*)(vt + ((size_t)b * H_ + h) * D_ * S_) +
      (size_t)(t >> 4) * 8192 + sw;
  unsigned char* lkd = lK + wv * 1024;

  f32x4 oacc[8][2] = {};
  float m_run[2] = {-__builtin_inff(), -__builtin_inff()};
  float l_run[2] = {0.f, 0.f};
  f32x4 sacc[8][2];
  union PW { unsigned int u[4]; short8 s; };
  PW pp[2][4];
  float coef[2];

  auto STAGE = [&](int n) {
    size_t kvK = (size_t)n * 1572864;  // 128 s-rows * 12288 B
    size_t kvV = (size_t)n * 256;      // 128 kv cols * 2 B
    unsigned char* vd = lds + 32768 + ((n & 1) << 15) + wv * 1024;
#pragma unroll
    for (int i = 0; i < 4; ++i) {
      glds16(gkb + kvK + i * 393216, lkd + i * 8192);
      glds16(gvb + kvV + i * 262144, vd + i * 8192);
    }
  };

  auto QK = [&]() {
    __builtin_amdgcn_s_setprio(1);
#pragma unroll
    for (int kf = 0; kf < 8; ++kf) {
      int kvr = kf * 16 + lo;
      int swz = (kvr & 7) << 4;
      sacc[kf][0] = f32x4{0.f, 0.f, 0.f, 0.f};
      sacc[kf][1] = f32x4{0.f, 0.f, 0.f, 0.f};
#pragma unroll
      for (int ks = 0; ks < 4; ++ks) {
        short8 kfr = *(const short8*)(lK + kvr * 256 + ((ks * 64 + hi * 16) ^ swz));
        sacc[kf][0] = __builtin_amdgcn_mfma_f32_16x16x32_bf16(kfr, qf[0][ks], sacc[kf][0], 0, 0, 0);
        sacc[kf][1] = __builtin_amdgcn_mfma_f32_16x16x32_bf16(kfr, qf[1][ks], sacc[kf][1], 0, 0, 0);
      }
    }
    __builtin_amdgcn_s_setprio(0);
  };

  auto PV = [&](const unsigned char* vb) {
#pragma unroll
    for (int ks = 0; ks < 4; ++ks) {
#pragma unroll
      for (int df = 0; df < 8; ++df) {
        int dr = df * 16 + lo;
        short8 vf = *(const short8*)(vb + dr * 256 + ((ks * 64 + hi * 16) ^ ((dr & 7) << 4)));
        oacc[df][0] = __builtin_amdgcn_mfma_f32_16x16x32_bf16(vf, pp[0][ks].s, oacc[df][0], 0, 0, 0);
        oacc[df][1] = __builtin_amdgcn_mfma_f32_16x16x32_bf16(vf, pp[1][ks].s, oacc[df][1], 0, 0, 0);
      }
    }
  };

  auto SOFTMAX = [&]() {
    float m2[2], li[2];
#pragma unroll
    for (int qj = 0; qj < 2; ++qj) {
      float mloc = -__builtin_inff();
#pragma unroll
      for (int kf = 0; kf < 8; ++kf)
#pragma unroll
        for (int r = 0; r < 4; ++r) mloc = fmaxf(mloc, sacc[kf][qj][r]);
      mloc = fmaxf(mloc, __shfl_xor(mloc, 16));
      mloc = fmaxf(mloc, __shfl_xor(mloc, 32));
      m2[qj] = mloc * c1;
      float lloc = 0.f;
#pragma unroll
      for (int kf = 0; kf < 8; ++kf)
#pragma unroll
        for (int r = 0; r < 4; ++r) {
          float p = exp2f_(fmaf(sacc[kf][qj][r], c1, -m2[qj]));
          sacc[kf][qj][r] = p;
          lloc += p;
        }
      lloc += __shfl_xor(lloc, 16);
      lloc += __shfl_xor(lloc, 32);
      li[qj] = lloc;  // = l_ij
    }
    if (__all(m2[0] <= m_run[0] && m2[1] <= m_run[1])) {
      // exact skip: m_new == m_run, alpha == 1
#pragma unroll
      for (int qj = 0; qj < 2; ++qj) {
        coef[qj] = exp2f_(m2[qj] - m_run[qj]) * li[qj];
        l_run[qj] += coef[qj];
      }
    } else {
      float alpha[2];
#pragma unroll
      for (int qj = 0; qj < 2; ++qj) {
        float mn = fmaxf(m_run[qj], m2[qj]);
        alpha[qj] = exp2f_(m_run[qj] - mn);
        coef[qj] = exp2f_(m2[qj] - mn) * li[qj];
        l_run[qj] = alpha[qj] * l_run[qj] + coef[qj];
        m_run[qj] = mn;
      }
#pragma unroll
      for (int df = 0; df < 8; ++df)
#pragma unroll
        for (int qj = 0; qj < 2; ++qj)
#pragma unroll
          for (int r = 0; r < 4; ++r) oacc[df][qj][r] *= alpha[qj];
    }
  };

  auto PACK = [&]() {
#pragma unroll
    for (int qj = 0; qj < 2; ++qj) {
      float cf = coef[qj];
#pragma unroll
      for (int ks = 0; ks < 4; ++ks) {
        unsigned int a0 = cvt_pk_bf16(sacc[2 * ks][qj][0] * cf, sacc[2 * ks][qj][1] * cf);
        unsigned int b0 = cvt_pk_bf16(sacc[2 * ks + 1][qj][0] * cf, sacc[2 * ks + 1][qj][1] * cf);
        unsigned int a1 = cvt_pk_bf16(sacc[2 * ks][qj][2] * cf, sacc[2 * ks][qj][3] * cf);
        unsigned int b1 = cvt_pk_bf16(sacc[2 * ks + 1][qj][2] * cf, sacc[2 * ks + 1][qj][3] * cf);
        asm("v_permlane32_swap_b32 %0, %1" : "+v"(a0), "+v"(b0));
        asm("v_permlane16_swap_b32 %0, %1" : "+v"(a0), "+v"(b0));
        asm("v_permlane32_swap_b32 %0, %1" : "+v"(a1), "+v"(b1));
        asm("v_permlane16_swap_b32 %0, %1" : "+v"(a1), "+v"(b1));
        pp[qj][ks].u[0] = a0;
        pp[qj][ks].u[1] = a1;
        pp[qj][ks].u[2] = b0;
        pp[qj][ks].u[3] = b1;
      }
    }
  };

  // ---- pipeline ----
  STAGE(0);
  VMC(0);
  BAR();
  QK();
  SOFTMAX();
  BAR();       // all waves done reading K(0) before STAGE(1) overwrites lK
  STAGE(1);    // K(1)->lK, V(1)->vb1 (V(0) in vb0 intact)
  PACK();

  for (int jb = 1; jb < 32; ++jb) {
    VMC(0);    // stage(jb) landed
    BAR();
    QK();                                            // K(jb) from lK
    PV(lds + 32768 + (((jb - 1) & 1) << 15));        // V(jb-1), pp(jb-1)
    SOFTMAX();                                       // VALU; interleaves with PV
    BAR();     // lK + V(jb-1) reads done before restage
    if (jb < 31) STAGE(jb + 1);                      // V -> vb[(jb+1)&1] == vb[(jb-1)&1]
    PACK();
  }
  PV(lds + 65536);  // tile 31, V from vb1

  // epilogue: out[q][d] = oacc^T / l_run, transpose via lds[0..64K), store
#pragma unroll
  for (int qj = 0; qj < 2; ++qj) {
    int rq = wv * 32 + qj * 16 + lo;
    int swzq = (rq & 7) << 4;
    float inv = 1.0f / l_run[qj];
#pragma unroll
    for (int df = 0; df < 8; ++df) {
      uint2 pk;
      pk.x = cvt_pk_bf16(oacc[df][qj][0] * inv, oacc[df][qj][1] * inv);
      pk.y = cvt_pk_bf16(oacc[df][qj][2] * inv, oacc[df][qj][3] * inv);
      *(uint2*)(lds + rq * 256 + ((df * 32 + hi * 8) ^ swzq)) = pk;
    }
  }
  __syncthreads();
#pragma unroll
  for (int i = 0; i < 8; ++i) {
    int row = i * 32 + (t >> 4);
    int c = t & 15;
    uint4 val = *(const uint4*)(lds + row * 256 + ((c * 16) ^ ((row & 7) << 4)));
    unsigned short* dst = abuf + (((size_t)b * S_ + q0 + row) * H_ + h) * D_ + c * 8;
    *(uint4*)dst = val;
  }
}

extern "C" void kernel_launch(void* const* d_in, const int* in_sizes, int n_in,
                              void* d_out, int out_size, void* d_ws, size_t ws_size,
                              hipStream_t stream) {
  const float* x = (const float*)d_in[0];
  const float* w_qkv = (const float*)d_in[1];
  const float* w_out = (const float*)d_in[2];
  const float* b_out = (const float*)d_in[3];
  float* out = (float*)d_out;
  char* ws = (char*)d_ws;

  unsigned short* xb    = (unsigned short*)(ws);
  unsigned short* wqkvb = (unsigned short*)(ws + 33554432);
  unsigned short* woutb = (unsigned short*)(ws + 58720256);
  unsigned short* qkvb  = (unsigned short*)(ws + 67108864);
  unsigned short* vtb   = (unsigned short*)(ws + 167772160);
  unsigned short* abuf  = xb;  // x dead after gemm1; reuse

  cvtk3<<<2048, 256, 0, stream>>>(x, w_qkv, w_out, xb, wqkvb, woutb);

  gemm256<0><<<768, 512, 0, stream>>>(xb, wqkvb, (void*)qkvb, nullptr,
                                      B_ * S_, 3 * E_, E_, 24);
  transpose_v<<<1024, 256, 0, stream>>>(qkvb, vtb);
  attn_fwd<<<512, 512, 0, stream>>>(qkvb, vtb, abuf);
  gemm256<1><<<256, 512, 0, stream>>>(abuf, woutb, (void*)out, b_out,
                                      B_ * S_, E_, E_, 8);
}

// Round 12
// 635.248 us; speedup vs baseline: 1.1191x; 1.1191x over previous
//
#include <hip/hip_runtime.h>
#include <hip/hip_bf16.h>
#include <stdint.h>

#define DEV __device__ __forceinline__

typedef __attribute__((ext_vector_type(8))) short short8;
typedef __attribute__((ext_vector_type(4))) float f32x4;

#define B_ 2
#define S_ 4096
#define E_ 2048
#define H_ 16
#define D_ 128

#define BAR() asm volatile("s_barrier" ::: "memory")
#define LGKM0() asm volatile("s_waitcnt lgkmcnt(0)" ::: "memory")
#define VMC(N) asm volatile("s_waitcnt vmcnt(" #N ")" ::: "memory")

DEV unsigned short f2bf(float x) {
  union { float f; uint32_t u; } a; a.f = x;
  uint32_t r = a.u + 0x7fffu + ((a.u >> 16) & 1u);
  return (unsigned short)(r >> 16);
}

DEV unsigned int cvt_pk_bf16(float a, float b) {
  unsigned int r;
  asm("v_cvt_pk_bf16_f32 %0, %1, %2" : "=v"(r) : "v"(a), "v"(b));
  return r;
}

DEV float exp2f_(float x) { return __builtin_amdgcn_exp2f(x); }

DEV void glds16(const void* g, void* l) {
  __builtin_amdgcn_global_load_lds(
      (const __attribute__((address_space(1))) uint32_t*)g,
      (__attribute__((address_space(3))) uint32_t*)l, 16, 0, 0);
}

// one kernel converts all three f32 inputs to bf16 (validated correct in R10)
__global__ __launch_bounds__(256) void cvtk3(
    const float* __restrict__ x, const float* __restrict__ wq,
    const float* __restrict__ wo, unsigned short* __restrict__ xb,
    unsigned short* __restrict__ wqb, unsigned short* __restrict__ wob) {
  const int n1 = (B_ * S_ * E_) / 4, n2 = (3 * E_ * E_) / 4, n3 = (E_ * E_) / 4;
  int i = blockIdx.x * blockDim.x + threadIdx.x;
  int stride = gridDim.x * blockDim.x;
  for (; i < n1 + n2 + n3; i += stride) {
    const float4* s;
    ushort4* d;
    int j;
    if (i < n1) { s = (const float4*)x; d = (ushort4*)xb; j = i; }
    else if (i < n1 + n2) { s = (const float4*)wq; d = (ushort4*)wqb; j = i - n1; }
    else { s = (const float4*)wo; d = (ushort4*)wob; j = i - n1 - n2; }
    float4 v = s[j];
    ushort4 o;
    o.x = f2bf(v.x); o.y = f2bf(v.y); o.z = f2bf(v.z); o.w = f2bf(v.w);
    d[j] = o;
  }
}

// C = A(MxK) * B(NxK)^T, 256x256 tile, BK=64, 8-phase schedule with counted
// vmcnt (T2+T3+T4+T5 per m201). 8 waves (2M x 4N), per-wave C = 128x64.
template<int OUT_F32>
__global__ __launch_bounds__(512, 2) void gemm256(
    const unsigned short* __restrict__ A,
    const unsigned short* __restrict__ Bm,
    void* __restrict__ Cp,
    const float* __restrict__ bias,
    int M, int N, int K, int nbn)
{
  __shared__ __align__(16) unsigned char lds[131072];
  const int NT = K >> 6;
  const int K2 = K * 2;
  int cpx = gridDim.x >> 3;
  int bid = (blockIdx.x & 7) * cpx + (blockIdx.x >> 3);
  int bm = bid / nbn, bn = bid % nbn;
  int m0 = bm * 256, n0 = bn * 256;
  int t = threadIdx.x, lane = t & 63, wv = t >> 6;
  int lo = lane & 15, hi = lane >> 4;
  int wm = wv >> 2, wn = wv & 3;

  int colsw = ((t & 7) * 16) ^ (((t >> 3) & 7) << 4);
  const unsigned char* gA = (const unsigned char*)A + (size_t)(m0 + (t >> 3)) * K2 + colsw;
  const unsigned char* gB = (const unsigned char*)Bm + (size_t)(n0 + (t >> 3)) * K2 + colsw;

  int swzl = (lo & 7) << 4;
  int colk0 = (hi * 16) ^ swzl;
  int colk1 = (64 + hi * 16) ^ swzl;
  unsigned char* rdA = lds + wm * 16384 + lo * 128;
  unsigned char* rdB = lds + 32768 + (wn >> 1) * 16384 + ((wn & 1) * 64 + lo) * 128;

  f32x4 acc[8][4] = {};

  auto STG = [&](int isA, int d, int h, int kt) {
    if (kt >= NT) return;
    const unsigned char* g = (isA ? gA : gB) + (size_t)h * 128 * K2 + (size_t)kt * 128;
    unsigned char* l = lds + (isA ? 0 : 32768) + d * 65536 + h * 16384 + wv * 1024;
    glds16(g, l);
    glds16(g + (size_t)64 * K2, l + 8192);
  };
  auto DSA = [&](int d, int g4, int colk, short8* dst) {
#pragma unroll
    for (int i = 0; i < 4; ++i)
      dst[i] = *(const short8*)(rdA + d * 65536 + (g4 * 4 + i) * 2048 + colk);
  };
  auto DSB = [&](int d, int colk, short8* dst) {
#pragma unroll
    for (int i = 0; i < 4; ++i)
      dst[i] = *(const short8*)(rdB + d * 65536 + i * 2048 + colk);
  };
  auto MM = [&](int g4, short8* a, short8* b) {
    __builtin_amdgcn_s_setprio(1);
#pragma unroll
    for (int i = 0; i < 4; ++i)
#pragma unroll
      for (int j = 0; j < 4; ++j)
        acc[g4 * 4 + i][j] =
            __builtin_amdgcn_mfma_f32_16x16x32_bf16(a[i], b[j], acc[g4 * 4 + i][j], 0, 0, 0);
    __builtin_amdgcn_s_setprio(0);
  };

  STG(1, 0, 0, 0); STG(1, 0, 1, 0); STG(0, 0, 0, 0); STG(0, 0, 1, 0);
  STG(0, 1, 0, 1); STG(0, 1, 1, 1);
  VMC(4);
  BAR();

  short8 aT[4], aU[4], b0[4], b1[4];
  const int TL = (NT >> 1) - 1;
  for (int it = 0; it <= TL; ++it) {
    int j0 = 2 * it;
    DSA(0, 0, colk0, aT); DSB(0, colk0, b0);
    STG(1, 1, 0, j0 + 1);
    BAR(); MM(0, aT, b0); LGKM0(); BAR();
    DSA(0, 1, colk0, aU); DSB(0, colk1, b1);
    STG(1, 1, 1, j0 + 1);
    BAR(); MM(1, aU, b0); LGKM0(); BAR();
    DSA(0, 0, colk1, aT);
    STG(0, 0, 0, j0 + 2);
    BAR(); MM(0, aT, b1); LGKM0(); BAR();
    DSA(0, 1, colk1, aU);
    STG(0, 0, 1, j0 + 2);
    BAR(); MM(1, aU, b1); LGKM0();
    if (it == TL) { VMC(0); } else { VMC(4); }
    BAR();
    DSA(1, 0, colk0, aT); DSB(1, colk0, b0);
    STG(1, 0, 0, j0 + 2);
    BAR(); MM(0, aT, b0); LGKM0(); BAR();
    DSA(1, 1, colk0, aU); DSB(1, colk1, b1);
    STG(1, 0, 1, j0 + 2);
    BAR(); MM(1, aU, b0); LGKM0(); BAR();
    DSA(1, 0, colk1, aT);
    STG(0, 1, 0, j0 + 3);
    BAR(); MM(0, aT, b1); LGKM0(); BAR();
    DSA(1, 1, colk1, aU);
    STG(0, 1, 1, j0 + 3);
    BAR(); MM(1, aU, b1); LGKM0(); VMC(4);
    BAR();
  }

  if constexpr (OUT_F32) {
    float* C = (float*)Cp;
#pragma unroll
    for (int mf = 0; mf < 8; ++mf)
#pragma unroll
      for (int nf = 0; nf < 4; ++nf) {
        int row = m0 + wm * 128 + mf * 16 + hi * 4;
        int col = n0 + wn * 64 + nf * 16 + lo;
        float bv = bias[col];
#pragma unroll
        for (int r = 0; r < 4; ++r)
          C[(size_t)(row + r) * N + col] = acc[mf][nf][r] + bv;
      }
  } else {
    unsigned short* C = (unsigned short*)Cp;
#pragma unroll
    for (int mf = 0; mf < 8; ++mf)
#pragma unroll
      for (int nf = 0; nf < 4; ++nf) {
        int row = m0 + wm * 128 + mf * 16 + hi * 4;
        int col = n0 + wn * 64 + nf * 16 + lo;
#pragma unroll
        for (int r = 0; r < 4; ++r)
          C[(size_t)(row + r) * N + col] = f2bf(acc[mf][nf][r]);
      }
  }
}

// vt[b,h,d,s] = qkv[b,s,2,h,d]
__global__ __launch_bounds__(256) void transpose_v(const unsigned short* __restrict__ qkv,
                                                   unsigned short* __restrict__ vt) {
  __shared__ __align__(16) unsigned char tl[32768];
  int bid = blockIdx.x;
  int st = bid & 31, bh = bid >> 5;
  int h = bh & 15, b = bh >> 4;
  int s0 = st * 128;
  int t = threadIdx.x, c = t & 15, rr = t >> 4;
#pragma unroll
  for (int i = 0; i < 8; ++i) {
    int s = rr + i * 16;
    const unsigned short* g = qkv + ((((size_t)b * S_ + s0 + s) * 3 + 2) * H_ + h) * D_ + c * 8;
    *(uint4*)(tl + s * 256 + ((c * 16) ^ (((s >> 3) & 7) << 4))) = *(const uint4*)g;
  }
  __syncthreads();
#pragma unroll
  for (int i = 0; i < 8; ++i) {
    int d = rr + i * 16;
    unsigned int w[4];
#pragma unroll
    for (int jj = 0; jj < 4; ++jj) {
      int s_a = c * 8 + jj * 2;
      unsigned int u0 = *(const unsigned short*)(tl + s_a * 256 + ((d * 2) ^ ((c & 7) << 4)));
      unsigned int u1 = *(const unsigned short*)(tl + (s_a + 1) * 256 + ((d * 2) ^ ((c & 7) << 4)));
      w[jj] = u0 | (u1 << 16);
    }
    uint4 val; val.x = w[0]; val.y = w[1]; val.z = w[2]; val.w = w[3];
    unsigned short* g = vt + (((size_t)b * H_ + h) * D_ + d) * S_ + s0 + c * 8;
    *(uint4*)g = val;
  }
}

// Flash attention, reference's extra l_ij semantics, KV block = 128.
// R8 structure (known-good 383 us): same-tile PV, P in registers via permlane
// pack (distinct-value operands only), K/V single-buffered 64K LDS,
// __shfl_xor softmax reductions.
__global__ __launch_bounds__(512, 2) void attn_fwd(
    const unsigned short* __restrict__ qkv,  // [B,S,3,H,D] bf16
    const unsigned short* __restrict__ vt,   // [B,H,D,S] bf16
    unsigned short* __restrict__ abuf)       // [B,S,H*D] bf16
{
  __shared__ __align__(16) unsigned char lds[65536];
  unsigned char* lK = lds;
  unsigned char* lV = lds + 32768;

  int bid = (blockIdx.x & 7) * 64 + (blockIdx.x >> 3);
  int qb = bid & 15, bh = bid >> 4;
  int h = bh & 15, b = bh >> 4;
  int t = threadIdx.x, lane = t & 63, wv = t >> 6;
  int hi = lane >> 4, lo = lane & 15;
  int q0 = qb * 256;
  const float c1 = 0.12751744f;  // (1/sqrt(128)) * log2(e)

  short8 qf[2][4];
#pragma unroll
  for (int qj = 0; qj < 2; ++qj) {
    const unsigned short* qbase =
        qkv + ((((size_t)b * S_ + q0 + wv * 32 + qj * 16 + lo) * 3 + 0) * H_ + h) * D_;
#pragma unroll
    for (int ks = 0; ks < 4; ++ks)
      qf[qj][ks] = *(const short8*)(qbase + ks * 32 + hi * 8);
  }

  int sw = ((t & 15) * 16) ^ (((t >> 4) & 7) << 4);
  const unsigned char* gkb =
      (const unsigned char*)(qkv + (((size_t)b * S_ * 3 + 1) * H_ + h) * D_) +
      (size_t)(t >> 4) * 12288 + sw;
  const unsigned char* gvb =
      (const unsigned char*)(vt + ((size_t)b * H_ + h) * D_ * S_) +
      (size_t)(t >> 4) * 8192 + sw;
  unsigned char* lkd = lK + wv * 1024;
  unsigned char* lvd = lV + wv * 1024;

  f32x4 oacc[8][2] = {};
  float m_run[2] = {-__builtin_inff(), -__builtin_inff()};
  float l_run[2] = {0.f, 0.f};
  union PW { unsigned int u[4]; short8 s; };
  PW pp[2][4];

#pragma unroll
  for (int i = 0; i < 4; ++i) {
    glds16(gkb + i * 393216, lkd + i * 8192);
    glds16(gvb + i * 262144, lvd + i * 8192);
  }

  for (int jb = 0; jb < 32; ++jb) {
    VMC(0);
    BAR();

    f32x4 sacc[8][2];
    __builtin_amdgcn_s_setprio(1);
#pragma unroll
    for (int kf = 0; kf < 8; ++kf) {
      int kvr = kf * 16 + lo;
      int swz = (kvr & 7) << 4;
      sacc[kf][0] = f32x4{0.f, 0.f, 0.f, 0.f};
      sacc[kf][1] = f32x4{0.f, 0.f, 0.f, 0.f};
#pragma unroll
      for (int ks = 0; ks < 4; ++ks) {
        short8 kfr = *(const short8*)(lK + kvr * 256 + ((ks * 64 + hi * 16) ^ swz));
        sacc[kf][0] = __builtin_amdgcn_mfma_f32_16x16x32_bf16(kfr, qf[0][ks], sacc[kf][0], 0, 0, 0);
        sacc[kf][1] = __builtin_amdgcn_mfma_f32_16x16x32_bf16(kfr, qf[1][ks], sacc[kf][1], 0, 0, 0);
      }
    }
    __builtin_amdgcn_s_setprio(0);

    float m2[2], li[2], coef[2];
#pragma unroll
    for (int qj = 0; qj < 2; ++qj) {
      float mloc = -__builtin_inff();
#pragma unroll
      for (int kf = 0; kf < 8; ++kf)
#pragma unroll
        for (int r = 0; r < 4; ++r) mloc = fmaxf(mloc, sacc[kf][qj][r]);
      mloc = fmaxf(mloc, __shfl_xor(mloc, 16));
      mloc = fmaxf(mloc, __shfl_xor(mloc, 32));
      m2[qj] = mloc * c1;
      float lloc = 0.f;
#pragma unroll
      for (int kf = 0; kf < 8; ++kf)
#pragma unroll
        for (int r = 0; r < 4; ++r) {
          float p = exp2f_(fmaf(sacc[kf][qj][r], c1, -m2[qj]));
          sacc[kf][qj][r] = p;
          lloc += p;
        }
      lloc += __shfl_xor(lloc, 16);
      lloc += __shfl_xor(lloc, 32);
      li[qj] = lloc;
    }

    if (__all(m2[0] <= m_run[0] && m2[1] <= m_run[1])) {
      // exact skip: m_new == m_run, alpha == 1
#pragma unroll
      for (int qj = 0; qj < 2; ++qj) {
        coef[qj] = exp2f_(m2[qj] - m_run[qj]) * li[qj];
        l_run[qj] += coef[qj];
      }
    } else {
      float alpha[2];
#pragma unroll
      for (int qj = 0; qj < 2; ++qj) {
        float mn = fmaxf(m_run[qj], m2[qj]);
        alpha[qj] = exp2f_(m_run[qj] - mn);
        coef[qj] = exp2f_(m2[qj] - mn) * li[qj];
        l_run[qj] = alpha[qj] * l_run[qj] + coef[qj];
        m_run[qj] = mn;
      }
#pragma unroll
      for (int df = 0; df < 8; ++df)
#pragma unroll
        for (int qj = 0; qj < 2; ++qj)
#pragma unroll
          for (int r = 0; r < 4; ++r) oacc[df][qj][r] *= alpha[qj];
    }

#pragma unroll
    for (int qj = 0; qj < 2; ++qj) {
      float cf = coef[qj];
#pragma unroll
      for (int ks = 0; ks < 4; ++ks) {
        unsigned int a0 = cvt_pk_bf16(sacc[2 * ks][qj][0] * cf, sacc[2 * ks][qj][1] * cf);
        unsigned int b0 = cvt_pk_bf16(sacc[2 * ks + 1][qj][0] * cf, sacc[2 * ks + 1][qj][1] * cf);
        unsigned int a1 = cvt_pk_bf16(sacc[2 * ks][qj][2] * cf, sacc[2 * ks][qj][3] * cf);
        unsigned int b1 = cvt_pk_bf16(sacc[2 * ks + 1][qj][2] * cf, sacc[2 * ks + 1][qj][3] * cf);
        asm("v_permlane32_swap_b32 %0, %1" : "+v"(a0), "+v"(b0));
        asm("v_permlane16_swap_b32 %0, %1" : "+v"(a0), "+v"(b0));
        asm("v_permlane32_swap_b32 %0, %1" : "+v"(a1), "+v"(b1));
        asm("v_permlane16_swap_b32 %0, %1" : "+v"(a1), "+v"(b1));
        pp[qj][ks].u[0] = a0;
        pp[qj][ks].u[1] = a1;
        pp[qj][ks].u[2] = b0;
        pp[qj][ks].u[3] = b1;
      }
    }

    __builtin_amdgcn_s_setprio(1);
#pragma unroll
    for (int ks = 0; ks < 4; ++ks) {
#pragma unroll
      for (int df = 0; df < 8; ++df) {
        int dr = df * 16 + lo;
        short8 vf = *(const short8*)(lV + dr * 256 + ((ks * 64 + hi * 16) ^ ((dr & 7) << 4)));
        oacc[df][0] = __builtin_amdgcn_mfma_f32_16x16x32_bf16(vf, pp[0][ks].s, oacc[df][0], 0, 0, 0);
        oacc[df][1] = __builtin_amdgcn_mfma_f32_16x16x32_bf16(vf, pp[1][ks].s, oacc[df][1], 0, 0, 0);
      }
    }
    __builtin_amdgcn_s_setprio(0);

    BAR();
    if (jb < 31) {
      size_t kvK = (size_t)(jb + 1) * 1572864;
      size_t kvV = (size_t)(jb + 1) * 256;
#pragma unroll
      for (int i = 0; i < 4; ++i) {
        glds16(gkb + kvK + i * 393216, lkd + i * 8192);
        glds16(gvb + kvV + i * 262144, lvd + i * 8192);
      }
    }
  }

  BAR();
#pragma unroll
  for (int qj = 0; qj < 2; ++qj) {
    int rq = wv * 32 + qj * 16 + lo;
    int swzq = (rq & 7) << 4;
    float inv = 1.0f / l_run[qj];
#pragma unroll
    for (int df = 0; df < 8; ++df) {
      uint2 pk;
      pk.x = cvt_pk_bf16(oacc[df][qj][0] * inv, oacc[df][qj][1] * inv);
      pk.y = cvt_pk_bf16(oacc[df][qj][2] * inv, oacc[df][qj][3] * inv);
      *(uint2*)(lds + rq * 256 + ((df * 32 + hi * 8) ^ swzq)) = pk;
    }
  }
  __syncthreads();
#pragma unroll
  for (int i = 0; i < 8; ++i) {
    int row = i * 32 + (t >> 4);
    int c = t & 15;
    uint4 val = *(const uint4*)(lds + row * 256 + ((c * 16) ^ ((row & 7) << 4)));
    unsigned short* dst = abuf + (((size_t)b * S_ + q0 + row) * H_ + h) * D_ + c * 8;
    *(uint4*)dst = val;
  }
}

extern "C" void kernel_launch(void* const* d_in, const int* in_sizes, int n_in,
                              void* d_out, int out_size, void* d_ws, size_t ws_size,
                              hipStream_t stream) {
  const float* x = (const float*)d_in[0];
  const float* w_qkv = (const float*)d_in[1];
  const float* w_out = (const float*)d_in[2];
  const float* b_out = (const float*)d_in[3];
  float* out = (float*)d_out;
  char* ws = (char*)d_ws;

  unsigned short* xb    = (unsigned short*)(ws);
  unsigned short* wqkvb = (unsigned short*)(ws + 33554432);
  unsigned short* woutb = (unsigned short*)(ws + 58720256);
  unsigned short* qkvb  = (unsigned short*)(ws + 67108864);
  unsigned short* vtb   = (unsigned short*)(ws + 167772160);
  unsigned short* abuf  = xb;  // x dead after gemm1; reuse

  cvtk3<<<2048, 256, 0, stream>>>(x, w_qkv, w_out, xb, wqkvb, woutb);

  gemm256<0><<<768, 512, 0, stream>>>(xb, wqkvb, (void*)qkvb, nullptr,
                                      B_ * S_, 3 * E_, E_, 24);
  transpose_v<<<1024, 256, 0, stream>>>(qkvb, vtb);
  attn_fwd<<<512, 512, 0, stream>>>(qkvb, vtb, abuf);
  gemm256<1><<<256, 512, 0, stream>>>(abuf, woutb, (void*)out, b_out,
                                      B_ * S_, E_, E_, 8);
}

// Round 13
// 626.207 us; speedup vs baseline: 1.1353x; 1.0144x over previous
//
#include <hip/hip_runtime.h>
#include <hip/hip_bf16.h>
#include <stdint.h>

#define DEV __device__ __forceinline__

typedef __attribute__((ext_vector_type(8))) short short8;
typedef __attribute__((ext_vector_type(4))) float f32x4;

#define B_ 2
#define S_ 4096
#define E_ 2048
#define H_ 16
#define D_ 128

#define BAR() asm volatile("s_barrier" ::: "memory")
#define LGKM0() asm volatile("s_waitcnt lgkmcnt(0)" ::: "memory")
#define VMC(N) asm volatile("s_waitcnt vmcnt(" #N ")" ::: "memory")

DEV unsigned short f2bf(float x) {
  union { float f; uint32_t u; } a; a.f = x;
  uint32_t r = a.u + 0x7fffu + ((a.u >> 16) & 1u);
  return (unsigned short)(r >> 16);
}

DEV unsigned int cvt_pk_bf16(float a, float b) {
  unsigned int r;
  asm("v_cvt_pk_bf16_f32 %0, %1, %2" : "=v"(r) : "v"(a), "v"(b));
  return r;
}

DEV float exp2f_(float x) { return __builtin_amdgcn_exp2f(x); }

DEV void glds16(const void* g, void* l) {
  __builtin_amdgcn_global_load_lds(
      (const __attribute__((address_space(1))) uint32_t*)g,
      (__attribute__((address_space(3))) uint32_t*)l, 16, 0, 0);
}

// one kernel converts all three f32 inputs to bf16 (validated correct in R10)
__global__ __launch_bounds__(256) void cvtk3(
    const float* __restrict__ x, const float* __restrict__ wq,
    const float* __restrict__ wo, unsigned short* __restrict__ xb,
    unsigned short* __restrict__ wqb, unsigned short* __restrict__ wob) {
  const int n1 = (B_ * S_ * E_) / 4, n2 = (3 * E_ * E_) / 4, n3 = (E_ * E_) / 4;
  int i = blockIdx.x * blockDim.x + threadIdx.x;
  int stride = gridDim.x * blockDim.x;
  for (; i < n1 + n2 + n3; i += stride) {
    const float4* s;
    ushort4* d;
    int j;
    if (i < n1) { s = (const float4*)x; d = (ushort4*)xb; j = i; }
    else if (i < n1 + n2) { s = (const float4*)wq; d = (ushort4*)wqb; j = i - n1; }
    else { s = (const float4*)wo; d = (ushort4*)wob; j = i - n1 - n2; }
    float4 v = s[j];
    ushort4 o;
    o.x = f2bf(v.x); o.y = f2bf(v.y); o.z = f2bf(v.z); o.w = f2bf(v.w);
    d[j] = o;
  }
}

// C = A(MxK) * B(NxK)^T, 256x256 tile, BK=64, 8-phase schedule with counted
// vmcnt (T2+T3+T4+T5 per m201). 8 waves (2M x 4N), per-wave C = 128x64.
// VSPLIT=1 (gemm1): tile-columns bn>=16 are the V part of qkv -> store the
// 256x256 tile TRANSPOSED to vt[b,h,d,s] via LDS instead of writing qkv.
template<int OUT_F32, int VSPLIT>
__global__ __launch_bounds__(512, 2) void gemm256(
    const unsigned short* __restrict__ A,
    const unsigned short* __restrict__ Bm,
    void* __restrict__ Cp,
    const float* __restrict__ bias,
    unsigned short* __restrict__ vt,
    int M, int N, int K, int nbn)
{
  __shared__ __align__(16) unsigned char lds[131072];
  const int NT = K >> 6;
  const int K2 = K * 2;
  int cpx = gridDim.x >> 3;
  int bid = (blockIdx.x & 7) * cpx + (blockIdx.x >> 3);
  int bm = bid / nbn, bn = bid % nbn;
  int m0 = bm * 256, n0 = bn * 256;
  int t = threadIdx.x, lane = t & 63, wv = t >> 6;
  int lo = lane & 15, hi = lane >> 4;
  int wm = wv >> 2, wn = wv & 3;

  int colsw = ((t & 7) * 16) ^ (((t >> 3) & 7) << 4);
  const unsigned char* gA = (const unsigned char*)A + (size_t)(m0 + (t >> 3)) * K2 + colsw;
  const unsigned char* gB = (const unsigned char*)Bm + (size_t)(n0 + (t >> 3)) * K2 + colsw;

  int swzl = (lo & 7) << 4;
  int colk0 = (hi * 16) ^ swzl;
  int colk1 = (64 + hi * 16) ^ swzl;
  unsigned char* rdA = lds + wm * 16384 + lo * 128;
  unsigned char* rdB = lds + 32768 + (wn >> 1) * 16384 + ((wn & 1) * 64 + lo) * 128;

  f32x4 acc[8][4] = {};

  auto STG = [&](int isA, int d, int h, int kt) {
    if (kt >= NT) return;
    const unsigned char* g = (isA ? gA : gB) + (size_t)h * 128 * K2 + (size_t)kt * 128;
    unsigned char* l = lds + (isA ? 0 : 32768) + d * 65536 + h * 16384 + wv * 1024;
    glds16(g, l);
    glds16(g + (size_t)64 * K2, l + 8192);
  };
  auto DSA = [&](int d, int g4, int colk, short8* dst) {
#pragma unroll
    for (int i = 0; i < 4; ++i)
      dst[i] = *(const short8*)(rdA + d * 65536 + (g4 * 4 + i) * 2048 + colk);
  };
  auto DSB = [&](int d, int colk, short8* dst) {
#pragma unroll
    for (int i = 0; i < 4; ++i)
      dst[i] = *(const short8*)(rdB + d * 65536 + i * 2048 + colk);
  };
  auto MM = [&](int g4, short8* a, short8* b) {
    __builtin_amdgcn_s_setprio(1);
#pragma unroll
    for (int i = 0; i < 4; ++i)
#pragma unroll
      for (int j = 0; j < 4; ++j)
        acc[g4 * 4 + i][j] =
            __builtin_amdgcn_mfma_f32_16x16x32_bf16(a[i], b[j], acc[g4 * 4 + i][j], 0, 0, 0);
    __builtin_amdgcn_s_setprio(0);
  };

  STG(1, 0, 0, 0); STG(1, 0, 1, 0); STG(0, 0, 0, 0); STG(0, 0, 1, 0);
  STG(0, 1, 0, 1); STG(0, 1, 1, 1);
  VMC(4);
  BAR();

  short8 aT[4], aU[4], b0[4], b1[4];
  const int TL = (NT >> 1) - 1;
  for (int it = 0; it <= TL; ++it) {
    int j0 = 2 * it;
    DSA(0, 0, colk0, aT); DSB(0, colk0, b0);
    STG(1, 1, 0, j0 + 1);
    BAR(); MM(0, aT, b0); LGKM0(); BAR();
    DSA(0, 1, colk0, aU); DSB(0, colk1, b1);
    STG(1, 1, 1, j0 + 1);
    BAR(); MM(1, aU, b0); LGKM0(); BAR();
    DSA(0, 0, colk1, aT);
    STG(0, 0, 0, j0 + 2);
    BAR(); MM(0, aT, b1); LGKM0(); BAR();
    DSA(0, 1, colk1, aU);
    STG(0, 0, 1, j0 + 2);
    BAR(); MM(1, aU, b1); LGKM0();
    if (it == TL) { VMC(0); } else { VMC(4); }
    BAR();
    DSA(1, 0, colk0, aT); DSB(1, colk0, b0);
    STG(1, 0, 0, j0 + 2);
    BAR(); MM(0, aT, b0); LGKM0(); BAR();
    DSA(1, 1, colk0, aU); DSB(1, colk1, b1);
    STG(1, 0, 1, j0 + 2);
    BAR(); MM(1, aU, b0); LGKM0(); BAR();
    DSA(1, 0, colk1, aT);
    STG(0, 1, 0, j0 + 3);
    BAR(); MM(0, aT, b1); LGKM0(); BAR();
    DSA(1, 1, colk1, aU);
    STG(0, 1, 1, j0 + 3);
    BAR(); MM(1, aU, b1); LGKM0(); VMC(4);
    BAR();
  }

  if constexpr (VSPLIT) {
    if (bn >= 16) {
      // V part: transpose the 256x256 tile through LDS, store to vt[b,h,d,s].
      // After the loop all LDS reads are MFMA-consumed and vmcnt==0.
      // LDS layout: [col 256][row 256] bf16, byte = col*512 + (row*2 ^ ((col&7)<<4)).
#pragma unroll
      for (int mf = 0; mf < 8; ++mf)
#pragma unroll
        for (int nf = 0; nf < 4; ++nf) {
          int row0 = wm * 128 + mf * 16 + hi * 4;
          int col = wn * 64 + nf * 16 + lo;
          uint2 pk;
          pk.x = (unsigned int)f2bf(acc[mf][nf][0]) | ((unsigned int)f2bf(acc[mf][nf][1]) << 16);
          pk.y = (unsigned int)f2bf(acc[mf][nf][2]) | ((unsigned int)f2bf(acc[mf][nf][3]) << 16);
          *(uint2*)(lds + col * 512 + ((row0 * 2) ^ ((col & 7) << 4))) = pk;
        }
      __syncthreads();
      // 512 threads: 2 per column, each stores 16 x 16B (col total 512B = 256 s)
      int col = t & 255;
      int half = t >> 8;
      int nv = n0 + col - 4096;           // v-dim index within [0, 2048)
      int hh = nv >> 7, dd = nv & 127;
      int b = m0 >> 12, s0 = m0 & 4095;
      unsigned short* vrow = vt + (((size_t)b * H_ + hh) * D_ + dd) * S_ + s0;
#pragma unroll
      for (int jj = 0; jj < 16; ++jj) {
        int j = half * 16 + jj;           // covers s_local 8j..8j+7
        uint4 v = *(const uint4*)(lds + col * 512 + 16 * (j ^ (col & 7)));
        *(uint4*)(vrow + j * 8) = v;
      }
      return;
    }
  }

  if constexpr (OUT_F32) {
    float* C = (float*)Cp;
#pragma unroll
    for (int mf = 0; mf < 8; ++mf)
#pragma unroll
      for (int nf = 0; nf < 4; ++nf) {
        int row = m0 + wm * 128 + mf * 16 + hi * 4;
        int col = n0 + wn * 64 + nf * 16 + lo;
        float bv = bias[col];
#pragma unroll
        for (int r = 0; r < 4; ++r)
          C[(size_t)(row + r) * N + col] = acc[mf][nf][r] + bv;
      }
  } else {
    unsigned short* C = (unsigned short*)Cp;
#pragma unroll
    for (int mf = 0; mf < 8; ++mf)
#pragma unroll
      for (int nf = 0; nf < 4; ++nf) {
        int row = m0 + wm * 128 + mf * 16 + hi * 4;
        int col = n0 + wn * 64 + nf * 16 + lo;
#pragma unroll
        for (int r = 0; r < 4; ++r)
          C[(size_t)(row + r) * N + col] = f2bf(acc[mf][nf][r]);
      }
  }
}

// Flash attention, reference's extra l_ij semantics, KV block = 128.
// R8 structure (known-good 383 us): same-tile PV, P in registers via permlane
// pack (distinct-value operands only), K/V single-buffered 64K LDS,
// __shfl_xor softmax reductions.
__global__ __launch_bounds__(512, 2) void attn_fwd(
    const unsigned short* __restrict__ qkv,  // [B,S,3,H,D] bf16
    const unsigned short* __restrict__ vt,   // [B,H,D,S] bf16
    unsigned short* __restrict__ abuf)       // [B,S,H*D] bf16
{
  __shared__ __align__(16) unsigned char lds[65536];
  unsigned char* lK = lds;
  unsigned char* lV = lds + 32768;

  int bid = (blockIdx.x & 7) * 64 + (blockIdx.x >> 3);
  int qb = bid & 15, bh = bid >> 4;
  int h = bh & 15, b = bh >> 4;
  int t = threadIdx.x, lane = t & 63, wv = t >> 6;
  int hi = lane >> 4, lo = lane & 15;
  int q0 = qb * 256;
  const float c1 = 0.12751744f;  // (1/sqrt(128)) * log2(e)

  short8 qf[2][4];
#pragma unroll
  for (int qj = 0; qj < 2; ++qj) {
    const unsigned short* qbase =
        qkv + ((((size_t)b * S_ + q0 + wv * 32 + qj * 16 + lo) * 3 + 0) * H_ + h) * D_;
#pragma unroll
    for (int ks = 0; ks < 4; ++ks)
      qf[qj][ks] = *(const short8*)(qbase + ks * 32 + hi * 8);
  }

  int sw = ((t & 15) * 16) ^ (((t >> 4) & 7) << 4);
  const unsigned char* gkb =
      (const unsigned char*)(qkv + (((size_t)b * S_ * 3 + 1) * H_ + h) * D_) +
      (size_t)(t >> 4) * 12288 + sw;
  const unsigned char* gvb =
      (const unsigned char*)(vt + ((size_t)b * H_ + h) * D_ * S_) +
      (size_t)(t >> 4) * 8192 + sw;
  unsigned char* lkd = lK + wv * 1024;
  unsigned char* lvd = lV + wv * 1024;

  f32x4 oacc[8][2] = {};
  float m_run[2] = {-__builtin_inff(), -__builtin_inff()};
  float l_run[2] = {0.f, 0.f};
  union PW { unsigned int u[4]; short8 s; };
  PW pp[2][4];

#pragma unroll
  for (int i = 0; i < 4; ++i) {
    glds16(gkb + i * 393216, lkd + i * 8192);
    glds16(gvb + i * 262144, lvd + i * 8192);
  }

  for (int jb = 0; jb < 32; ++jb) {
    VMC(0);
    BAR();

    f32x4 sacc[8][2];
    __builtin_amdgcn_s_setprio(1);
#pragma unroll
    for (int kf = 0; kf < 8; ++kf) {
      int kvr = kf * 16 + lo;
      int swz = (kvr & 7) << 4;
      sacc[kf][0] = f32x4{0.f, 0.f, 0.f, 0.f};
      sacc[kf][1] = f32x4{0.f, 0.f, 0.f, 0.f};
#pragma unroll
      for (int ks = 0; ks < 4; ++ks) {
        short8 kfr = *(const short8*)(lK + kvr * 256 + ((ks * 64 + hi * 16) ^ swz));
        sacc[kf][0] = __builtin_amdgcn_mfma_f32_16x16x32_bf16(kfr, qf[0][ks], sacc[kf][0], 0, 0, 0);
        sacc[kf][1] = __builtin_amdgcn_mfma_f32_16x16x32_bf16(kfr, qf[1][ks], sacc[kf][1], 0, 0, 0);
      }
    }
    __builtin_amdgcn_s_setprio(0);

    float m2[2], li[2], coef[2];
#pragma unroll
    for (int qj = 0; qj < 2; ++qj) {
      float mloc = -__builtin_inff();
#pragma unroll
      for (int kf = 0; kf < 8; ++kf)
#pragma unroll
        for (int r = 0; r < 4; ++r) mloc = fmaxf(mloc, sacc[kf][qj][r]);
      mloc = fmaxf(mloc, __shfl_xor(mloc, 16));
      mloc = fmaxf(mloc, __shfl_xor(mloc, 32));
      m2[qj] = mloc * c1;
      float lloc = 0.f;
#pragma unroll
      for (int kf = 0; kf < 8; ++kf)
#pragma unroll
        for (int r = 0; r < 4; ++r) {
          float p = exp2f_(fmaf(sacc[kf][qj][r], c1, -m2[qj]));
          sacc[kf][qj][r] = p;
          lloc += p;
        }
      lloc += __shfl_xor(lloc, 16);
      lloc += __shfl_xor(lloc, 32);
      li[qj] = lloc;
    }

    if (__all(m2[0] <= m_run[0] && m2[1] <= m_run[1])) {
      // exact skip: m_new == m_run, alpha == 1
#pragma unroll
      for (int qj = 0; qj < 2; ++qj) {
        coef[qj] = exp2f_(m2[qj] - m_run[qj]) * li[qj];
        l_run[qj] += coef[qj];
      }
    } else {
      float alpha[2];
#pragma unroll
      for (int qj = 0; qj < 2; ++qj) {
        float mn = fmaxf(m_run[qj], m2[qj]);
        alpha[qj] = exp2f_(m_run[qj] - mn);
        coef[qj] = exp2f_(m2[qj] - mn) * li[qj];
        l_run[qj] = alpha[qj] * l_run[qj] + coef[qj];
        m_run[qj] = mn;
      }
#pragma unroll
      for (int df = 0; df < 8; ++df)
#pragma unroll
        for (int qj = 0; qj < 2; ++qj)
#pragma unroll
          for (int r = 0; r < 4; ++r) oacc[df][qj][r] *= alpha[qj];
    }

#pragma unroll
    for (int qj = 0; qj < 2; ++qj) {
      float cf = coef[qj];
#pragma unroll
      for (int ks = 0; ks < 4; ++ks) {
        unsigned int a0 = cvt_pk_bf16(sacc[2 * ks][qj][0] * cf, sacc[2 * ks][qj][1] * cf);
        unsigned int b0 = cvt_pk_bf16(sacc[2 * ks + 1][qj][0] * cf, sacc[2 * ks + 1][qj][1] * cf);
        unsigned int a1 = cvt_pk_bf16(sacc[2 * ks][qj][2] * cf, sacc[2 * ks][qj][3] * cf);
        unsigned int b1 = cvt_pk_bf16(sacc[2 * ks + 1][qj][2] * cf, sacc[2 * ks + 1][qj][3] * cf);
        asm("v_permlane32_swap_b32 %0, %1" : "+v"(a0), "+v"(b0));
        asm("v_permlane16_swap_b32 %0, %1" : "+v"(a0), "+v"(b0));
        asm("v_permlane32_swap_b32 %0, %1" : "+v"(a1), "+v"(b1));
        asm("v_permlane16_swap_b32 %0, %1" : "+v"(a1), "+v"(b1));
        pp[qj][ks].u[0] = a0;
        pp[qj][ks].u[1] = a1;
        pp[qj][ks].u[2] = b0;
        pp[qj][ks].u[3] = b1;
      }
    }

    __builtin_amdgcn_s_setprio(1);
#pragma unroll
    for (int ks = 0; ks < 4; ++ks) {
#pragma unroll
      for (int df = 0; df < 8; ++df) {
        int dr = df * 16 + lo;
        short8 vf = *(const short8*)(lV + dr * 256 + ((ks * 64 + hi * 16) ^ ((dr & 7) << 4)));
        oacc[df][0] = __builtin_amdgcn_mfma_f32_16x16x32_bf16(vf, pp[0][ks].s, oacc[df][0], 0, 0, 0);
        oacc[df][1] = __builtin_amdgcn_mfma_f32_16x16x32_bf16(vf, pp[1][ks].s, oacc[df][1], 0, 0, 0);
      }
    }
    __builtin_amdgcn_s_setprio(0);

    BAR();
    if (jb < 31) {
      size_t kvK = (size_t)(jb + 1) * 1572864;
      size_t kvV = (size_t)(jb + 1) * 256;
#pragma unroll
      for (int i = 0; i < 4; ++i) {
        glds16(gkb + kvK + i * 393216, lkd + i * 8192);
        glds16(gvb + kvV + i * 262144, lvd + i * 8192);
      }
    }
  }

  BAR();
#pragma unroll
  for (int qj = 0; qj < 2; ++qj) {
    int rq = wv * 32 + qj * 16 + lo;
    int swzq = (rq & 7) << 4;
    float inv = 1.0f / l_run[qj];
#pragma unroll
    for (int df = 0; df < 8; ++df) {
      uint2 pk;
      pk.x = cvt_pk_bf16(oacc[df][qj][0] * inv, oacc[df][qj][1] * inv);
      pk.y = cvt_pk_bf16(oacc[df][qj][2] * inv, oacc[df][qj][3] * inv);
      *(uint2*)(lds + rq * 256 + ((df * 32 + hi * 8) ^ swzq)) = pk;
    }
  }
  __syncthreads();
#pragma unroll
  for (int i = 0; i < 8; ++i) {
    int row = i * 32 + (t >> 4);
    int c = t & 15;
    uint4 val = *(const uint4*)(lds + row * 256 + ((c * 16) ^ ((row & 7) << 4)));
    unsigned short* dst = abuf + (((size_t)b * S_ + q0 + row) * H_ + h) * D_ + c * 8;
    *(uint4*)dst = val;
  }
}

extern "C" void kernel_launch(void* const* d_in, const int* in_sizes, int n_in,
                              void* d_out, int out_size, void* d_ws, size_t ws_size,
                              hipStream_t stream) {
  const float* x = (const float*)d_in[0];
  const float* w_qkv = (const float*)d_in[1];
  const float* w_out = (const float*)d_in[2];
  const float* b_out = (const float*)d_in[3];
  float* out = (float*)d_out;
  char* ws = (char*)d_ws;

  unsigned short* xb    = (unsigned short*)(ws);
  unsigned short* wqkvb = (unsigned short*)(ws + 33554432);
  unsigned short* woutb = (unsigned short*)(ws + 58720256);
  unsigned short* qkvb  = (unsigned short*)(ws + 67108864);
  unsigned short* vtb   = (unsigned short*)(ws + 167772160);
  unsigned short* abuf  = xb;  // x dead after gemm1; reuse

  cvtk3<<<2048, 256, 0, stream>>>(x, w_qkv, w_out, xb, wqkvb, woutb);

  // gemm1: Q,K columns -> qkvb; V columns (bn>=16) -> vtb transposed
  gemm256<0, 1><<<768, 512, 0, stream>>>(xb, wqkvb, (void*)qkvb, nullptr, vtb,
                                         B_ * S_, 3 * E_, E_, 24);
  attn_fwd<<<512, 512, 0, stream>>>(qkvb, vtb, abuf);
  gemm256<1, 0><<<256, 512, 0, stream>>>(abuf, woutb, (void*)out, b_out, nullptr,
                                         B_ * S_, E_, E_, 8);
}

// Round 14
// 625.153 us; speedup vs baseline: 1.1372x; 1.0017x over previous
//
#include <hip/hip_runtime.h>
#include <hip/hip_bf16.h>
#include <stdint.h>

#define DEV __device__ __forceinline__

typedef __attribute__((ext_vector_type(8))) short short8;
typedef __attribute__((ext_vector_type(4))) float f32x4;

#define B_ 2
#define S_ 4096
#define E_ 2048
#define H_ 16
#define D_ 128

#define BAR() asm volatile("s_barrier" ::: "memory")
#define LGKM0() asm volatile("s_waitcnt lgkmcnt(0)" ::: "memory")
#define VMC(N) asm volatile("s_waitcnt vmcnt(" #N ")" ::: "memory")

DEV unsigned short f2bf(float x) {
  union { float f; uint32_t u; } a; a.f = x;
  uint32_t r = a.u + 0x7fffu + ((a.u >> 16) & 1u);
  return (unsigned short)(r >> 16);
}

DEV unsigned int cvt_pk_bf16(float a, float b) {
  unsigned int r;
  asm("v_cvt_pk_bf16_f32 %0, %1, %2" : "=v"(r) : "v"(a), "v"(b));
  return r;
}

DEV float exp2f_(float x) { return __builtin_amdgcn_exp2f(x); }

DEV void glds16(const void* g, void* l) {
  __builtin_amdgcn_global_load_lds(
      (const __attribute__((address_space(1))) uint32_t*)g,
      (__attribute__((address_space(3))) uint32_t*)l, 16, 0, 0);
}

// f32 -> bf16 for the three inputs; block-static region partition (no per-iter
// divergence): blocks [0,1024) -> x, [1024,1792) -> w_qkv, [1792,2048) -> w_out.
__global__ __launch_bounds__(256) void cvtk3(
    const float* __restrict__ x, const float* __restrict__ wq,
    const float* __restrict__ wo, unsigned short* __restrict__ xb,
    unsigned short* __restrict__ wqb, unsigned short* __restrict__ wob) {
  const int n1 = (B_ * S_ * E_) / 4, n2 = (3 * E_ * E_) / 4, n3 = (E_ * E_) / 4;
  int bid = blockIdx.x;
  const float4* s;
  ushort4* d;
  int n, b0, nb;
  if (bid < 1024)      { s = (const float4*)x;  d = (ushort4*)xb;  n = n1; b0 = 0;    nb = 1024; }
  else if (bid < 1792) { s = (const float4*)wq; d = (ushort4*)wqb; n = n2; b0 = 1024; nb = 768; }
  else                 { s = (const float4*)wo; d = (ushort4*)wob; n = n3; b0 = 1792; nb = 256; }
  for (int i = (bid - b0) * 256 + threadIdx.x; i < n; i += nb * 256) {
    float4 v = s[i];
    ushort4 o;
    o.x = f2bf(v.x); o.y = f2bf(v.y); o.z = f2bf(v.z); o.w = f2bf(v.w);
    d[i] = o;
  }
}

// C = A(MxK) * B(NxK)^T, 256x256 tile, BK=64, 8-phase schedule with counted
// vmcnt (T2+T3+T4+T5 per m201). 8 waves (2M x 4N), per-wave C = 128x64.
// VSPLIT=1 (gemm1): tile-columns bn>=16 are the V part of qkv -> store the
// 256x256 tile TRANSPOSED to vt[b,h,d,s] via LDS instead of writing qkv.
template<int OUT_F32, int VSPLIT>
__global__ __launch_bounds__(512, 2) void gemm256(
    const unsigned short* __restrict__ A,
    const unsigned short* __restrict__ Bm,
    void* __restrict__ Cp,
    const float* __restrict__ bias,
    unsigned short* __restrict__ vt,
    int M, int N, int K, int nbn)
{
  __shared__ __align__(16) unsigned char lds[131072];
  const int NT = K >> 6;
  const int K2 = K * 2;
  int cpx = gridDim.x >> 3;
  int bid = (blockIdx.x & 7) * cpx + (blockIdx.x >> 3);
  int bm = bid / nbn, bn = bid % nbn;
  int m0 = bm * 256, n0 = bn * 256;
  int t = threadIdx.x, lane = t & 63, wv = t >> 6;
  int lo = lane & 15, hi = lane >> 4;
  int wm = wv >> 2, wn = wv & 3;

  int colsw = ((t & 7) * 16) ^ (((t >> 3) & 7) << 4);
  const unsigned char* gA = (const unsigned char*)A + (size_t)(m0 + (t >> 3)) * K2 + colsw;
  const unsigned char* gB = (const unsigned char*)Bm + (size_t)(n0 + (t >> 3)) * K2 + colsw;

  int swzl = (lo & 7) << 4;
  int colk0 = (hi * 16) ^ swzl;
  int colk1 = (64 + hi * 16) ^ swzl;
  unsigned char* rdA = lds + wm * 16384 + lo * 128;
  unsigned char* rdB = lds + 32768 + (wn >> 1) * 16384 + ((wn & 1) * 64 + lo) * 128;

  f32x4 acc[8][4] = {};

  auto STG = [&](int isA, int d, int h, int kt) {
    if (kt >= NT) return;
    const unsigned char* g = (isA ? gA : gB) + (size_t)h * 128 * K2 + (size_t)kt * 128;
    unsigned char* l = lds + (isA ? 0 : 32768) + d * 65536 + h * 16384 + wv * 1024;
    glds16(g, l);
    glds16(g + (size_t)64 * K2, l + 8192);
  };
  auto DSA = [&](int d, int g4, int colk, short8* dst) {
#pragma unroll
    for (int i = 0; i < 4; ++i)
      dst[i] = *(const short8*)(rdA + d * 65536 + (g4 * 4 + i) * 2048 + colk);
  };
  auto DSB = [&](int d, int colk, short8* dst) {
#pragma unroll
    for (int i = 0; i < 4; ++i)
      dst[i] = *(const short8*)(rdB + d * 65536 + i * 2048 + colk);
  };
  auto MM = [&](int g4, short8* a, short8* b) {
    __builtin_amdgcn_s_setprio(1);
#pragma unroll
    for (int i = 0; i < 4; ++i)
#pragma unroll
      for (int j = 0; j < 4; ++j)
        acc[g4 * 4 + i][j] =
            __builtin_amdgcn_mfma_f32_16x16x32_bf16(a[i], b[j], acc[g4 * 4 + i][j], 0, 0, 0);
    __builtin_amdgcn_s_setprio(0);
  };

  STG(1, 0, 0, 0); STG(1, 0, 1, 0); STG(0, 0, 0, 0); STG(0, 0, 1, 0);
  STG(0, 1, 0, 1); STG(0, 1, 1, 1);
  VMC(4);
  BAR();

  short8 aT[4], aU[4], b0v[4], b1v[4];
  const int TL = (NT >> 1) - 1;
  for (int it = 0; it <= TL; ++it) {
    int j0 = 2 * it;
    DSA(0, 0, colk0, aT); DSB(0, colk0, b0v);
    STG(1, 1, 0, j0 + 1);
    BAR(); MM(0, aT, b0v); LGKM0(); BAR();
    DSA(0, 1, colk0, aU); DSB(0, colk1, b1v);
    STG(1, 1, 1, j0 + 1);
    BAR(); MM(1, aU, b0v); LGKM0(); BAR();
    DSA(0, 0, colk1, aT);
    STG(0, 0, 0, j0 + 2);
    BAR(); MM(0, aT, b1v); LGKM0(); BAR();
    DSA(0, 1, colk1, aU);
    STG(0, 0, 1, j0 + 2);
    BAR(); MM(1, aU, b1v); LGKM0();
    if (it == TL) { VMC(0); } else { VMC(4); }
    BAR();
    DSA(1, 0, colk0, aT); DSB(1, colk0, b0v);
    STG(1, 0, 0, j0 + 2);
    BAR(); MM(0, aT, b0v); LGKM0(); BAR();
    DSA(1, 1, colk0, aU); DSB(1, colk1, b1v);
    STG(1, 0, 1, j0 + 2);
    BAR(); MM(1, aU, b0v); LGKM0(); BAR();
    DSA(1, 0, colk1, aT);
    STG(0, 1, 0, j0 + 3);
    BAR(); MM(0, aT, b1v); LGKM0(); BAR();
    DSA(1, 1, colk1, aU);
    STG(0, 1, 1, j0 + 3);
    BAR(); MM(1, aU, b1v); LGKM0(); VMC(4);
    BAR();
  }

  if constexpr (VSPLIT) {
    if (bn >= 16) {
      // V part: transpose the 256x256 tile through LDS, store to vt[b,h,d,s].
#pragma unroll
      for (int mf = 0; mf < 8; ++mf)
#pragma unroll
        for (int nf = 0; nf < 4; ++nf) {
          int row0 = wm * 128 + mf * 16 + hi * 4;
          int col = wn * 64 + nf * 16 + lo;
          uint2 pk;
          pk.x = (unsigned int)f2bf(acc[mf][nf][0]) | ((unsigned int)f2bf(acc[mf][nf][1]) << 16);
          pk.y = (unsigned int)f2bf(acc[mf][nf][2]) | ((unsigned int)f2bf(acc[mf][nf][3]) << 16);
          *(uint2*)(lds + col * 512 + ((row0 * 2) ^ ((col & 7) << 4))) = pk;
        }
      __syncthreads();
      int col = t & 255;
      int half = t >> 8;
      int nv = n0 + col - 4096;
      int hh = nv >> 7, dd = nv & 127;
      int b = m0 >> 12, s0 = m0 & 4095;
      unsigned short* vrow = vt + (((size_t)b * H_ + hh) * D_ + dd) * S_ + s0;
#pragma unroll
      for (int jj = 0; jj < 16; ++jj) {
        int j = half * 16 + jj;
        uint4 v = *(const uint4*)(lds + col * 512 + 16 * (j ^ (col & 7)));
        *(uint4*)(vrow + j * 8) = v;
      }
      return;
    }
  }

  if constexpr (OUT_F32) {
    float* C = (float*)Cp;
#pragma unroll
    for (int mf = 0; mf < 8; ++mf)
#pragma unroll
      for (int nf = 0; nf < 4; ++nf) {
        int row = m0 + wm * 128 + mf * 16 + hi * 4;
        int col = n0 + wn * 64 + nf * 16 + lo;
        float bv = bias[col];
#pragma unroll
        for (int r = 0; r < 4; ++r)
          C[(size_t)(row + r) * N + col] = acc[mf][nf][r] + bv;
      }
  } else {
    unsigned short* C = (unsigned short*)Cp;
#pragma unroll
    for (int mf = 0; mf < 8; ++mf)
#pragma unroll
      for (int nf = 0; nf < 4; ++nf) {
        int row = m0 + wm * 128 + mf * 16 + hi * 4;
        int col = n0 + wn * 64 + nf * 16 + lo;
#pragma unroll
        for (int r = 0; r < 4; ++r)
          C[(size_t)(row + r) * N + col] = f2bf(acc[mf][nf][r]);
      }
  }
}

// Flash attention, reference's extra l_ij semantics, KV block = 128.
// R8 structure (known-good 383 us) + tree-shaped softmax reductions
// (depth-5 max3/add trees instead of 32-deep serial chains).
__global__ __launch_bounds__(512, 2) void attn_fwd(
    const unsigned short* __restrict__ qkv,  // [B,S,3,H,D] bf16
    const unsigned short* __restrict__ vt,   // [B,H,D,S] bf16
    unsigned short* __restrict__ abuf)       // [B,S,H*D] bf16
{
  __shared__ __align__(16) unsigned char lds[65536];
  unsigned char* lK = lds;
  unsigned char* lV = lds + 32768;

  int bid = (blockIdx.x & 7) * 64 + (blockIdx.x >> 3);
  int qb = bid & 15, bh = bid >> 4;
  int h = bh & 15, b = bh >> 4;
  int t = threadIdx.x, lane = t & 63, wv = t >> 6;
  int hi = lane >> 4, lo = lane & 15;
  int q0 = qb * 256;
  const float c1 = 0.12751744f;  // (1/sqrt(128)) * log2(e)

  short8 qf[2][4];
#pragma unroll
  for (int qj = 0; qj < 2; ++qj) {
    const unsigned short* qbase =
        qkv + ((((size_t)b * S_ + q0 + wv * 32 + qj * 16 + lo) * 3 + 0) * H_ + h) * D_;
#pragma unroll
    for (int ks = 0; ks < 4; ++ks)
      qf[qj][ks] = *(const short8*)(qbase + ks * 32 + hi * 8);
  }

  int sw = ((t & 15) * 16) ^ (((t >> 4) & 7) << 4);
  const unsigned char* gkb =
      (const unsigned char*)(qkv + (((size_t)b * S_ * 3 + 1) * H_ + h) * D_) +
      (size_t)(t >> 4) * 12288 + sw;
  const unsigned char* gvb =
      (const unsigned char*)(vt + ((size_t)b * H_ + h) * D_ * S_) +
      (size_t)(t >> 4) * 8192 + sw;
  unsigned char* lkd = lK + wv * 1024;
  unsigned char* lvd = lV + wv * 1024;

  f32x4 oacc[8][2] = {};
  float m_run[2] = {-__builtin_inff(), -__builtin_inff()};
  float l_run[2] = {0.f, 0.f};
  union PW { unsigned int u[4]; short8 s; };
  PW pp[2][4];

#pragma unroll
  for (int i = 0; i < 4; ++i) {
    glds16(gkb + i * 393216, lkd + i * 8192);
    glds16(gvb + i * 262144, lvd + i * 8192);
  }

  for (int jb = 0; jb < 32; ++jb) {
    VMC(0);
    BAR();

    f32x4 sacc[8][2];
    __builtin_amdgcn_s_setprio(1);
#pragma unroll
    for (int kf = 0; kf < 8; ++kf) {
      int kvr = kf * 16 + lo;
      int swz = (kvr & 7) << 4;
      sacc[kf][0] = f32x4{0.f, 0.f, 0.f, 0.f};
      sacc[kf][1] = f32x4{0.f, 0.f, 0.f, 0.f};
#pragma unroll
      for (int ks = 0; ks < 4; ++ks) {
        short8 kfr = *(const short8*)(lK + kvr * 256 + ((ks * 64 + hi * 16) ^ swz));
        sacc[kf][0] = __builtin_amdgcn_mfma_f32_16x16x32_bf16(kfr, qf[0][ks], sacc[kf][0], 0, 0, 0);
        sacc[kf][1] = __builtin_amdgcn_mfma_f32_16x16x32_bf16(kfr, qf[1][ks], sacc[kf][1], 0, 0, 0);
      }
    }
    __builtin_amdgcn_s_setprio(0);

    float m2[2], li[2], coef[2];
#pragma unroll
    for (int qj = 0; qj < 2; ++qj) {
      // depth-5 max tree (fmaxf nesting fuses to v_max3)
      float mk[8];
#pragma unroll
      for (int kf = 0; kf < 8; ++kf)
        mk[kf] = fmaxf(fmaxf(sacc[kf][qj][0], sacc[kf][qj][1]),
                       fmaxf(sacc[kf][qj][2], sacc[kf][qj][3]));
      float ma = fmaxf(fmaxf(mk[0], mk[1]), fmaxf(mk[2], mk[3]));
      float mb = fmaxf(fmaxf(mk[4], mk[5]), fmaxf(mk[6], mk[7]));
      float mloc = fmaxf(ma, mb);
      mloc = fmaxf(mloc, __shfl_xor(mloc, 16));
      mloc = fmaxf(mloc, __shfl_xor(mloc, 32));
      m2[qj] = mloc * c1;
      // exp + depth-5 add tree
      float sk[8];
#pragma unroll
      for (int kf = 0; kf < 8; ++kf) {
        float p0 = exp2f_(fmaf(sacc[kf][qj][0], c1, -m2[qj]));
        float p1 = exp2f_(fmaf(sacc[kf][qj][1], c1, -m2[qj]));
        float p2 = exp2f_(fmaf(sacc[kf][qj][2], c1, -m2[qj]));
        float p3 = exp2f_(fmaf(sacc[kf][qj][3], c1, -m2[qj]));
        sacc[kf][qj][0] = p0; sacc[kf][qj][1] = p1;
        sacc[kf][qj][2] = p2; sacc[kf][qj][3] = p3;
        sk[kf] = (p0 + p1) + (p2 + p3);
      }
      float sa = (sk[0] + sk[1]) + (sk[2] + sk[3]);
      float sb = (sk[4] + sk[5]) + (sk[6] + sk[7]);
      float lloc = sa + sb;
      lloc += __shfl_xor(lloc, 16);
      lloc += __shfl_xor(lloc, 32);
      li[qj] = lloc;
    }

    if (__all(m2[0] <= m_run[0] && m2[1] <= m_run[1])) {
      // exact skip: m_new == m_run, alpha == 1
#pragma unroll
      for (int qj = 0; qj < 2; ++qj) {
        coef[qj] = exp2f_(m2[qj] - m_run[qj]) * li[qj];
        l_run[qj] += coef[qj];
      }
    } else {
      float alpha[2];
#pragma unroll
      for (int qj = 0; qj < 2; ++qj) {
        float mn = fmaxf(m_run[qj], m2[qj]);
        alpha[qj] = exp2f_(m_run[qj] - mn);
        coef[qj] = exp2f_(m2[qj] - mn) * li[qj];
        l_run[qj] = alpha[qj] * l_run[qj] + coef[qj];
        m_run[qj] = mn;
      }
#pragma unroll
      for (int df = 0; df < 8; ++df)
#pragma unroll
        for (int qj = 0; qj < 2; ++qj)
#pragma unroll
          for (int r = 0; r < 4; ++r) oacc[df][qj][r] *= alpha[qj];
    }

#pragma unroll
    for (int qj = 0; qj < 2; ++qj) {
      float cf = coef[qj];
#pragma unroll
      for (int ks = 0; ks < 4; ++ks) {
        unsigned int a0 = cvt_pk_bf16(sacc[2 * ks][qj][0] * cf, sacc[2 * ks][qj][1] * cf);
        unsigned int b0 = cvt_pk_bf16(sacc[2 * ks + 1][qj][0] * cf, sacc[2 * ks + 1][qj][1] * cf);
        unsigned int a1 = cvt_pk_bf16(sacc[2 * ks][qj][2] * cf, sacc[2 * ks][qj][3] * cf);
        unsigned int b1 = cvt_pk_bf16(sacc[2 * ks + 1][qj][2] * cf, sacc[2 * ks + 1][qj][3] * cf);
        asm("v_permlane32_swap_b32 %0, %1" : "+v"(a0), "+v"(b0));
        asm("v_permlane16_swap_b32 %0, %1" : "+v"(a0), "+v"(b0));
        asm("v_permlane32_swap_b32 %0, %1" : "+v"(a1), "+v"(b1));
        asm("v_permlane16_swap_b32 %0, %1" : "+v"(a1), "+v"(b1));
        pp[qj][ks].u[0] = a0;
        pp[qj][ks].u[1] = a1;
        pp[qj][ks].u[2] = b0;
        pp[qj][ks].u[3] = b1;
      }
    }

    __builtin_amdgcn_s_setprio(1);
#pragma unroll
    for (int ks = 0; ks < 4; ++ks) {
#pragma unroll
      for (int df = 0; df < 8; ++df) {
        int dr = df * 16 + lo;
        short8 vf = *(const short8*)(lV + dr * 256 + ((ks * 64 + hi * 16) ^ ((dr & 7) << 4)));
        oacc[df][0] = __builtin_amdgcn_mfma_f32_16x16x32_bf16(vf, pp[0][ks].s, oacc[df][0], 0, 0, 0);
        oacc[df][1] = __builtin_amdgcn_mfma_f32_16x16x32_bf16(vf, pp[1][ks].s, oacc[df][1], 0, 0, 0);
      }
    }
    __builtin_amdgcn_s_setprio(0);

    BAR();
    if (jb < 31) {
      size_t kvK = (size_t)(jb + 1) * 1572864;
      size_t kvV = (size_t)(jb + 1) * 256;
#pragma unroll
      for (int i = 0; i < 4; ++i) {
        glds16(gkb + kvK + i * 393216, lkd + i * 8192);
        glds16(gvb + kvV + i * 262144, lvd + i * 8192);
      }
    }
  }

  BAR();
#pragma unroll
  for (int qj = 0; qj < 2; ++qj) {
    int rq = wv * 32 + qj * 16 + lo;
    int swzq = (rq & 7) << 4;
    float inv = 1.0f / l_run[qj];
#pragma unroll
    for (int df = 0; df < 8; ++df) {
      uint2 pk;
      pk.x = cvt_pk_bf16(oacc[df][qj][0] * inv, oacc[df][qj][1] * inv);
      pk.y = cvt_pk_bf16(oacc[df][qj][2] * inv, oacc[df][qj][3] * inv);
      *(uint2*)(lds + rq * 256 + ((df * 32 + hi * 8) ^ swzq)) = pk;
    }
  }
  __syncthreads();
#pragma unroll
  for (int i = 0; i < 8; ++i) {
    int row = i * 32 + (t >> 4);
    int c = t & 15;
    uint4 val = *(const uint4*)(lds + row * 256 + ((c * 16) ^ ((row & 7) << 4)));
    unsigned short* dst = abuf + (((size_t)b * S_ + q0 + row) * H_ + h) * D_ + c * 8;
    *(uint4*)dst = val;
  }
}

extern "C" void kernel_launch(void* const* d_in, const int* in_sizes, int n_in,
                              void* d_out, int out_size, void* d_ws, size_t ws_size,
                              hipStream_t stream) {
  const float* x = (const float*)d_in[0];
  const float* w_qkv = (const float*)d_in[1];
  const float* w_out = (const float*)d_in[2];
  const float* b_out = (const float*)d_in[3];
  float* out = (float*)d_out;
  char* ws = (char*)d_ws;

  unsigned short* xb    = (unsigned short*)(ws);
  unsigned short* wqkvb = (unsigned short*)(ws + 33554432);
  unsigned short* woutb = (unsigned short*)(ws + 58720256);
  unsigned short* qkvb  = (unsigned short*)(ws + 67108864);
  unsigned short* vtb   = (unsigned short*)(ws + 167772160);
  unsigned short* abuf  = xb;  // x dead after gemm1; reuse

  cvtk3<<<2048, 256, 0, stream>>>(x, w_qkv, w_out, xb, wqkvb, woutb);

  // gemm1: Q,K columns -> qkvb; V columns (bn>=16) -> vtb transposed
  gemm256<0, 1><<<768, 512, 0, stream>>>(xb, wqkvb, (void*)qkvb, nullptr, vtb,
                                         B_ * S_, 3 * E_, E_, 24);
  attn_fwd<<<512, 512, 0, stream>>>(qkvb, vtb, abuf);
  gemm256<1, 0><<<256, 512, 0, stream>>>(abuf, woutb, (void*)out, b_out, nullptr,
                                         B_ * S_, E_, E_, 8);
}

// Round 16
// 604.990 us; speedup vs baseline: 1.1751x; 1.0333x over previous
//
#include <hip/hip_runtime.h>
#include <hip/hip_bf16.h>
#include <stdint.h>

#define DEV __device__ __forceinline__

typedef __attribute__((ext_vector_type(8))) short short8;
typedef __attribute__((ext_vector_type(4))) float f32x4;

#define B_ 2
#define S_ 4096
#define E_ 2048
#define H_ 16
#define D_ 128

#define BAR() asm volatile("s_barrier" ::: "memory")
#define LGKM0() asm volatile("s_waitcnt lgkmcnt(0)" ::: "memory")
#define VMC(N) asm volatile("s_waitcnt vmcnt(" #N ")" ::: "memory")

DEV unsigned short f2bf(float x) {
  union { float f; uint32_t u; } a; a.f = x;
  uint32_t r = a.u + 0x7fffu + ((a.u >> 16) & 1u);
  return (unsigned short)(r >> 16);
}

DEV unsigned int cvt_pk_bf16(float a, float b) {
  unsigned int r;
  asm("v_cvt_pk_bf16_f32 %0, %1, %2" : "=v"(r) : "v"(a), "v"(b));
  return r;
}

DEV float exp2f_(float x) { return __builtin_amdgcn_exp2f(x); }

DEV void glds16(const void* g, void* l) {
  __builtin_amdgcn_global_load_lds(
      (const __attribute__((address_space(1))) uint32_t*)g,
      (__attribute__((address_space(3))) uint32_t*)l, 16, 0, 0);
}

// f32 -> bf16 for the three inputs; block-static region partition.
__global__ __launch_bounds__(256) void cvtk3(
    const float* __restrict__ x, const float* __restrict__ wq,
    const float* __restrict__ wo, unsigned short* __restrict__ xb,
    unsigned short* __restrict__ wqb, unsigned short* __restrict__ wob) {
  const int n1 = (B_ * S_ * E_) / 4, n2 = (3 * E_ * E_) / 4, n3 = (E_ * E_) / 4;
  int bid = blockIdx.x;
  const float4* s;
  ushort4* d;
  int n, b0, nb;
  if (bid < 1024)      { s = (const float4*)x;  d = (ushort4*)xb;  n = n1; b0 = 0;    nb = 1024; }
  else if (bid < 1792) { s = (const float4*)wq; d = (ushort4*)wqb; n = n2; b0 = 1024; nb = 768; }
  else                 { s = (const float4*)wo; d = (ushort4*)wob; n = n3; b0 = 1792; nb = 256; }
  for (int i = (bid - b0) * 256 + threadIdx.x; i < n; i += nb * 256) {
    float4 v = s[i];
    ushort4 o;
    o.x = f2bf(v.x); o.y = f2bf(v.y); o.z = f2bf(v.z); o.w = f2bf(v.w);
    d[i] = o;
  }
}

// C = A(MxK) * B(NxK)^T, 256x256 tile, BK=64, 8-phase schedule with counted
// vmcnt (T2+T3+T4+T5 per m201). 8 waves (2M x 4N), per-wave C = 128x64.
// VSPLIT=1 (gemm1): tile-columns bn>=16 are the V part of qkv -> store the
// 256x256 tile TRANSPOSED to vt[b,h,d,s] via LDS instead of writing qkv.
template<int OUT_F32, int VSPLIT>
__global__ __launch_bounds__(512, 2) void gemm256(
    const unsigned short* __restrict__ A,
    const unsigned short* __restrict__ Bm,
    void* __restrict__ Cp,
    const float* __restrict__ bias,
    unsigned short* __restrict__ vt,
    int M, int N, int K, int nbn)
{
  __shared__ __align__(16) unsigned char lds[131072];
  const int NT = K >> 6;
  const int K2 = K * 2;
  int cpx = gridDim.x >> 3;
  int bid = (blockIdx.x & 7) * cpx + (blockIdx.x >> 3);
  int bm = bid / nbn, bn = bid % nbn;
  int m0 = bm * 256, n0 = bn * 256;
  int t = threadIdx.x, lane = t & 63, wv = t >> 6;
  int lo = lane & 15, hi = lane >> 4;
  int wm = wv >> 2, wn = wv & 3;

  int colsw = ((t & 7) * 16) ^ (((t >> 3) & 7) << 4);
  const unsigned char* gA = (const unsigned char*)A + (size_t)(m0 + (t >> 3)) * K2 + colsw;
  const unsigned char* gB = (const unsigned char*)Bm + (size_t)(n0 + (t >> 3)) * K2 + colsw;

  int swzl = (lo & 7) << 4;
  int colk0 = (hi * 16) ^ swzl;
  int colk1 = (64 + hi * 16) ^ swzl;
  unsigned char* rdA = lds + wm * 16384 + lo * 128;
  unsigned char* rdB = lds + 32768 + (wn >> 1) * 16384 + ((wn & 1) * 64 + lo) * 128;

  f32x4 acc[8][4] = {};

  auto STG = [&](int isA, int d, int h, int kt) {
    if (kt >= NT) return;
    const unsigned char* g = (isA ? gA : gB) + (size_t)h * 128 * K2 + (size_t)kt * 128;
    unsigned char* l = lds + (isA ? 0 : 32768) + d * 65536 + h * 16384 + wv * 1024;
    glds16(g, l);
    glds16(g + (size_t)64 * K2, l + 8192);
  };
  auto DSA = [&](int d, int g4, int colk, short8* dst) {
#pragma unroll
    for (int i = 0; i < 4; ++i)
      dst[i] = *(const short8*)(rdA + d * 65536 + (g4 * 4 + i) * 2048 + colk);
  };
  auto DSB = [&](int d, int colk, short8* dst) {
#pragma unroll
    for (int i = 0; i < 4; ++i)
      dst[i] = *(const short8*)(rdB + d * 65536 + i * 2048 + colk);
  };
  auto MM = [&](int g4, short8* a, short8* b) {
    __builtin_amdgcn_s_setprio(1);
#pragma unroll
    for (int i = 0; i < 4; ++i)
#pragma unroll
      for (int j = 0; j < 4; ++j)
        acc[g4 * 4 + i][j] =
            __builtin_amdgcn_mfma_f32_16x16x32_bf16(a[i], b[j], acc[g4 * 4 + i][j], 0, 0, 0);
    __builtin_amdgcn_s_setprio(0);
  };

  STG(1, 0, 0, 0); STG(1, 0, 1, 0); STG(0, 0, 0, 0); STG(0, 0, 1, 0);
  STG(0, 1, 0, 1); STG(0, 1, 1, 1);
  VMC(4);
  BAR();

  short8 aT[4], aU[4], b0v[4], b1v[4];
  const int TL = (NT >> 1) - 1;
  for (int it = 0; it <= TL; ++it) {
    int j0 = 2 * it;
    DSA(0, 0, colk0, aT); DSB(0, colk0, b0v);
    STG(1, 1, 0, j0 + 1);
    BAR(); MM(0, aT, b0v); LGKM0(); BAR();
    DSA(0, 1, colk0, aU); DSB(0, colk1, b1v);
    STG(1, 1, 1, j0 + 1);
    BAR(); MM(1, aU, b0v); LGKM0(); BAR();
    DSA(0, 0, colk1, aT);
    STG(0, 0, 0, j0 + 2);
    BAR(); MM(0, aT, b1v); LGKM0(); BAR();
    DSA(0, 1, colk1, aU);
    STG(0, 0, 1, j0 + 2);
    BAR(); MM(1, aU, b1v); LGKM0();
    if (it == TL) { VMC(0); } else { VMC(4); }
    BAR();
    DSA(1, 0, colk0, aT); DSB(1, colk0, b0v);
    STG(1, 0, 0, j0 + 2);
    BAR(); MM(0, aT, b0v); LGKM0(); BAR();
    DSA(1, 1, colk0, aU); DSB(1, colk1, b1v);
    STG(1, 0, 1, j0 + 2);
    BAR(); MM(1, aU, b0v); LGKM0(); BAR();
    DSA(1, 0, colk1, aT);
    STG(0, 1, 0, j0 + 3);
    BAR(); MM(0, aT, b1v); LGKM0(); BAR();
    DSA(1, 1, colk1, aU);
    STG(0, 1, 1, j0 + 3);
    BAR(); MM(1, aU, b1v); LGKM0(); VMC(4);
    BAR();
  }

  if constexpr (VSPLIT) {
    if (bn >= 16) {
#pragma unroll
      for (int mf = 0; mf < 8; ++mf)
#pragma unroll
        for (int nf = 0; nf < 4; ++nf) {
          int row0 = wm * 128 + mf * 16 + hi * 4;
          int col = wn * 64 + nf * 16 + lo;
          uint2 pk;
          pk.x = (unsigned int)f2bf(acc[mf][nf][0]) | ((unsigned int)f2bf(acc[mf][nf][1]) << 16);
          pk.y = (unsigned int)f2bf(acc[mf][nf][2]) | ((unsigned int)f2bf(acc[mf][nf][3]) << 16);
          *(uint2*)(lds + col * 512 + ((row0 * 2) ^ ((col & 7) << 4))) = pk;
        }
      __syncthreads();
      int col = t & 255;
      int half = t >> 8;
      int nv = n0 + col - 4096;
      int hh = nv >> 7, dd = nv & 127;
      int b = m0 >> 12, s0 = m0 & 4095;
      unsigned short* vrow = vt + (((size_t)b * H_ + hh) * D_ + dd) * S_ + s0;
#pragma unroll
      for (int jj = 0; jj < 16; ++jj) {
        int j = half * 16 + jj;
        uint4 v = *(const uint4*)(lds + col * 512 + 16 * (j ^ (col & 7)));
        *(uint4*)(vrow + j * 8) = v;
      }
      return;
    }
  }

  if constexpr (OUT_F32) {
    float* C = (float*)Cp;
#pragma unroll
    for (int mf = 0; mf < 8; ++mf)
#pragma unroll
      for (int nf = 0; nf < 4; ++nf) {
        int row = m0 + wm * 128 + mf * 16 + hi * 4;
        int col = n0 + wn * 64 + nf * 16 + lo;
        float bv = bias[col];
#pragma unroll
        for (int r = 0; r < 4; ++r)
          C[(size_t)(row + r) * N + col] = acc[mf][nf][r] + bv;
      }
  } else {
    unsigned short* C = (unsigned short*)Cp;
#pragma unroll
    for (int mf = 0; mf < 8; ++mf)
#pragma unroll
      for (int nf = 0; nf < 4; ++nf) {
        int row = m0 + wm * 128 + mf * 16 + hi * 4;
        int col = n0 + wn * 64 + nf * 16 + lo;
#pragma unroll
        for (int r = 0; r < 4; ++r)
          C[(size_t)(row + r) * N + col] = f2bf(acc[mf][nf][r]);
      }
  }
}

// Flash attention, reference's extra l_ij semantics, KV block = 128.
// R8 structure at 4 waves x 32 q = 128-q block, 64K LDS -> TWO independent
// blocks/CU (decoupled barrier domains). Per-wave state identical to R8.
// Staging: 8 rounds x 16 rows x 256B = 32KB per K and per V (FIXED: was 16).
__global__ __launch_bounds__(256, 2) void attn_fwd(
    const unsigned short* __restrict__ qkv,  // [B,S,3,H,D] bf16
    const unsigned short* __restrict__ vt,   // [B,H,D,S] bf16
    unsigned short* __restrict__ abuf)       // [B,S,H*D] bf16
{
  __shared__ __align__(16) unsigned char lds[65536];
  unsigned char* lK = lds;
  unsigned char* lV = lds + 32768;

  // XCD-chunked swizzle: 1024 blocks, 8 XCDs, 128 logical per XCD.
  int bid = (blockIdx.x & 7) * 128 + (blockIdx.x >> 3);
  int qb = bid & 31, bh = bid >> 5;
  int h = bh & 15, b = bh >> 4;
  int t = threadIdx.x, lane = t & 63, wv = t >> 6;
  int hi = lane >> 4, lo = lane & 15;
  int q0 = qb * 128;
  const float c1 = 0.12751744f;  // (1/sqrt(128)) * log2(e)

  short8 qf[2][4];
#pragma unroll
  for (int qj = 0; qj < 2; ++qj) {
    const unsigned short* qbase =
        qkv + ((((size_t)b * S_ + q0 + wv * 32 + qj * 16 + lo) * 3 + 0) * H_ + h) * D_;
#pragma unroll
    for (int ks = 0; ks < 4; ++ks)
      qf[qj][ks] = *(const short8*)(qbase + ks * 32 + hi * 8);
  }

  // staging: 256 threads, 8 rounds of 4KB (16 rows per round), rows 0..127.
  int sw = ((t & 15) * 16) ^ (((t >> 4) & 7) << 4);
  const unsigned char* gkb =
      (const unsigned char*)(qkv + (((size_t)b * S_ * 3 + 1) * H_ + h) * D_) +
      (size_t)(t >> 4) * 12288 + sw;
  const unsigned char* gvb =
      (const unsigned char*)(vt + ((size_t)b * H_ + h) * D_ * S_) +
      (size_t)(t >> 4) * 8192 + sw;
  unsigned char* lkd = lK + wv * 1024;
  unsigned char* lvd = lV + wv * 1024;

  f32x4 oacc[8][2] = {};
  float m_run[2] = {-__builtin_inff(), -__builtin_inff()};
  float l_run[2] = {0.f, 0.f};
  union PW { unsigned int u[4]; short8 s; };
  PW pp[2][4];

#pragma unroll
  for (int i = 0; i < 8; ++i) {
    glds16(gkb + (size_t)i * 196608, lkd + i * 4096);   // 16 K rows * 12288 B
    glds16(gvb + (size_t)i * 131072, lvd + i * 4096);   // 16 V rows * 8192 B
  }

  for (int jb = 0; jb < 32; ++jb) {
    VMC(0);
    BAR();

    f32x4 sacc[8][2];
    __builtin_amdgcn_s_setprio(1);
#pragma unroll
    for (int kf = 0; kf < 8; ++kf) {
      int kvr = kf * 16 + lo;
      int swz = (kvr & 7) << 4;
      sacc[kf][0] = f32x4{0.f, 0.f, 0.f, 0.f};
      sacc[kf][1] = f32x4{0.f, 0.f, 0.f, 0.f};
#pragma unroll
      for (int ks = 0; ks < 4; ++ks) {
        short8 kfr = *(const short8*)(lK + kvr * 256 + ((ks * 64 + hi * 16) ^ swz));
        sacc[kf][0] = __builtin_amdgcn_mfma_f32_16x16x32_bf16(kfr, qf[0][ks], sacc[kf][0], 0, 0, 0);
        sacc[kf][1] = __builtin_amdgcn_mfma_f32_16x16x32_bf16(kfr, qf[1][ks], sacc[kf][1], 0, 0, 0);
      }
    }
    __builtin_amdgcn_s_setprio(0);

    float m2[2], li[2], coef[2];
#pragma unroll
    for (int qj = 0; qj < 2; ++qj) {
      float mk[8];
#pragma unroll
      for (int kf = 0; kf < 8; ++kf)
        mk[kf] = fmaxf(fmaxf(sacc[kf][qj][0], sacc[kf][qj][1]),
                       fmaxf(sacc[kf][qj][2], sacc[kf][qj][3]));
      float ma = fmaxf(fmaxf(mk[0], mk[1]), fmaxf(mk[2], mk[3]));
      float mb = fmaxf(fmaxf(mk[4], mk[5]), fmaxf(mk[6], mk[7]));
      float mloc = fmaxf(ma, mb);
      mloc = fmaxf(mloc, __shfl_xor(mloc, 16));
      mloc = fmaxf(mloc, __shfl_xor(mloc, 32));
      m2[qj] = mloc * c1;
      float sk[8];
#pragma unroll
      for (int kf = 0; kf < 8; ++kf) {
        float p0 = exp2f_(fmaf(sacc[kf][qj][0], c1, -m2[qj]));
        float p1 = exp2f_(fmaf(sacc[kf][qj][1], c1, -m2[qj]));
        float p2 = exp2f_(fmaf(sacc[kf][qj][2], c1, -m2[qj]));
        float p3 = exp2f_(fmaf(sacc[kf][qj][3], c1, -m2[qj]));
        sacc[kf][qj][0] = p0; sacc[kf][qj][1] = p1;
        sacc[kf][qj][2] = p2; sacc[kf][qj][3] = p3;
        sk[kf] = (p0 + p1) + (p2 + p3);
      }
      float sa = (sk[0] + sk[1]) + (sk[2] + sk[3]);
      float sb = (sk[4] + sk[5]) + (sk[6] + sk[7]);
      float lloc = sa + sb;
      lloc += __shfl_xor(lloc, 16);
      lloc += __shfl_xor(lloc, 32);
      li[qj] = lloc;
    }

    if (__all(m2[0] <= m_run[0] && m2[1] <= m_run[1])) {
      // exact skip: m_new == m_run, alpha == 1
#pragma unroll
      for (int qj = 0; qj < 2; ++qj) {
        coef[qj] = exp2f_(m2[qj] - m_run[qj]) * li[qj];
        l_run[qj] += coef[qj];
      }
    } else {
      float alpha[2];
#pragma unroll
      for (int qj = 0; qj < 2; ++qj) {
        float mn = fmaxf(m_run[qj], m2[qj]);
        alpha[qj] = exp2f_(m_run[qj] - mn);
        coef[qj] = exp2f_(m2[qj] - mn) * li[qj];
        l_run[qj] = alpha[qj] * l_run[qj] + coef[qj];
        m_run[qj] = mn;
      }
#pragma unroll
      for (int df = 0; df < 8; ++df)
#pragma unroll
        for (int qj = 0; qj < 2; ++qj)
#pragma unroll
          for (int r = 0; r < 4; ++r) oacc[df][qj][r] *= alpha[qj];
    }

#pragma unroll
    for (int qj = 0; qj < 2; ++qj) {
      float cf = coef[qj];
#pragma unroll
      for (int ks = 0; ks < 4; ++ks) {
        unsigned int a0 = cvt_pk_bf16(sacc[2 * ks][qj][0] * cf, sacc[2 * ks][qj][1] * cf);
        unsigned int b0 = cvt_pk_bf16(sacc[2 * ks + 1][qj][0] * cf, sacc[2 * ks + 1][qj][1] * cf);
        unsigned int a1 = cvt_pk_bf16(sacc[2 * ks][qj][2] * cf, sacc[2 * ks][qj][3] * cf);
        unsigned int b1 = cvt_pk_bf16(sacc[2 * ks + 1][qj][2] * cf, sacc[2 * ks + 1][qj][3] * cf);
        asm("v_permlane32_swap_b32 %0, %1" : "+v"(a0), "+v"(b0));
        asm("v_permlane16_swap_b32 %0, %1" : "+v"(a0), "+v"(b0));
        asm("v_permlane32_swap_b32 %0, %1" : "+v"(a1), "+v"(b1));
        asm("v_permlane16_swap_b32 %0, %1" : "+v"(a1), "+v"(b1));
        pp[qj][ks].u[0] = a0;
        pp[qj][ks].u[1] = a1;
        pp[qj][ks].u[2] = b0;
        pp[qj][ks].u[3] = b1;
      }
    }

    __builtin_amdgcn_s_setprio(1);
#pragma unroll
    for (int ks = 0; ks < 4; ++ks) {
#pragma unroll
      for (int df = 0; df < 8; ++df) {
        int dr = df * 16 + lo;
        short8 vf = *(const short8*)(lV + dr * 256 + ((ks * 64 + hi * 16) ^ ((dr & 7) << 4)));
        oacc[df][0] = __builtin_amdgcn_mfma_f32_16x16x32_bf16(vf, pp[0][ks].s, oacc[df][0], 0, 0, 0);
        oacc[df][1] = __builtin_amdgcn_mfma_f32_16x16x32_bf16(vf, pp[1][ks].s, oacc[df][1], 0, 0, 0);
      }
    }
    __builtin_amdgcn_s_setprio(0);

    BAR();
    if (jb < 31) {
      size_t kvK = (size_t)(jb + 1) * 1572864;
      size_t kvV = (size_t)(jb + 1) * 256;
#pragma unroll
      for (int i = 0; i < 8; ++i) {
        glds16(gkb + kvK + (size_t)i * 196608, lkd + i * 4096);
        glds16(gvb + kvV + (size_t)i * 131072, lvd + i * 4096);
      }
    }
  }

  BAR();
#pragma unroll
  for (int qj = 0; qj < 2; ++qj) {
    int rq = wv * 32 + qj * 16 + lo;
    int swzq = (rq & 7) << 4;
    float inv = 1.0f / l_run[qj];
#pragma unroll
    for (int df = 0; df < 8; ++df) {
      uint2 pk;
      pk.x = cvt_pk_bf16(oacc[df][qj][0] * inv, oacc[df][qj][1] * inv);
      pk.y = cvt_pk_bf16(oacc[df][qj][2] * inv, oacc[df][qj][3] * inv);
      *(uint2*)(lds + rq * 256 + ((df * 32 + hi * 8) ^ swzq)) = pk;
    }
  }
  __syncthreads();
#pragma unroll
  for (int i = 0; i < 8; ++i) {
    int row = i * 16 + (t >> 4);
    int c = t & 15;
    uint4 val = *(const uint4*)(lds + row * 256 + ((c * 16) ^ ((row & 7) << 4)));
    unsigned short* dst = abuf + (((size_t)b * S_ + q0 + row) * H_ + h) * D_ + c * 8;
    *(uint4*)dst = val;
  }
}

extern "C" void kernel_launch(void* const* d_in, const int* in_sizes, int n_in,
                              void* d_out, int out_size, void* d_ws, size_t ws_size,
                              hipStream_t stream) {
  const float* x = (const float*)d_in[0];
  const float* w_qkv = (const float*)d_in[1];
  const float* w_out = (const float*)d_in[2];
  const float* b_out = (const float*)d_in[3];
  float* out = (float*)d_out;
  char* ws = (char*)d_ws;

  unsigned short* xb    = (unsigned short*)(ws);
  unsigned short* wqkvb = (unsigned short*)(ws + 33554432);
  unsigned short* woutb = (unsigned short*)(ws + 58720256);
  unsigned short* qkvb  = (unsigned short*)(ws + 67108864);
  unsigned short* vtb   = (unsigned short*)(ws + 167772160);
  unsigned short* abuf  = xb;  // x dead after gemm1; reuse

  cvtk3<<<2048, 256, 0, stream>>>(x, w_qkv, w_out, xb, wqkvb, woutb);

  // gemm1: Q,K columns -> qkvb; V columns (bn>=16) -> vtb transposed
  gemm256<0, 1><<<768, 512, 0, stream>>>(xb, wqkvb, (void*)qkvb, nullptr, vtb,
                                         B_ * S_, 3 * E_, E_, 24);
  attn_fwd<<<1024, 256, 0, stream>>>(qkvb, vtb, abuf);
  gemm256<1, 0><<<256, 512, 0, stream>>>(abuf, woutb, (void*)out, b_out, nullptr,
                                         B_ * S_, E_, E_, 8);
}